// Round 2
// baseline (856.363 us; speedup 1.0000x reference)
//
#include <hip/hip_runtime.h>

// GIN regressor: 3x [segment-sum aggregation -> (1+eps)*x+agg -> Linear/ReLU/Linear]
// -> global mean pool by graph -> fc.
// Strategy: build CSR (sorted-by-dst edge list) once per call, reuse for all 3
// layers; aggregation is gather-only (no float atomics), 2-way unrolled for MLP.
// GEMMs are fp32 vector (no fp32 MFMA on CDNA4) with W staged in LDS.

#define FEAT 128

// ---------------- CSR build ----------------
__global__ void hist_kernel(const int* __restrict__ dst, int* __restrict__ deg, int E) {
    int e = blockIdx.x * blockDim.x + threadIdx.x;
    if (e < E) atomicAdd(&deg[dst[e]], 1);
}

// single block, 1024 threads: in-place exclusive scan of off[0..n), writes off[n]=total,
// and copies the exclusive offsets into cursor[].
__global__ void scan_kernel(int* __restrict__ off, int* __restrict__ cursor, int n) {
    __shared__ int lsum[1024];
    int tid = threadIdx.x;
    int chunk = (n + 1023) / 1024;
    int start = tid * chunk;
    int end = start + chunk; if (end > n) end = n; if (start > n) start = n;
    int s = 0;
    for (int i = start; i < end; ++i) s += off[i];
    lsum[tid] = s;
    __syncthreads();
    // Hillis-Steele inclusive scan over 1024 partials
    for (int d = 1; d < 1024; d <<= 1) {
        int v = (tid >= d) ? lsum[tid - d] : 0;
        __syncthreads();
        lsum[tid] += v;
        __syncthreads();
    }
    int base = (tid == 0) ? 0 : lsum[tid - 1];
    for (int i = start; i < end; ++i) {
        int c = off[i];
        off[i] = base;
        cursor[i] = base;
        base += c;
    }
    if (tid == 1023) off[n] = lsum[1023];
}

__global__ void scatter_kernel(const int* __restrict__ src, const int* __restrict__ dst,
                               int* __restrict__ cursor, int* __restrict__ srcs, int E) {
    int e = blockIdx.x * blockDim.x + threadIdx.x;
    if (e < E) {
        int d = dst[e];
        int p = atomicAdd(&cursor[d], 1);
        srcs[p] = src[e];
    }
}

// counts[g] = #nodes with batch == g (batch sorted ascending)
__global__ void counts_kernel(const int* __restrict__ batch, int* __restrict__ counts,
                              int n, int g) {
    int i = blockIdx.x * blockDim.x + threadIdx.x;
    if (i >= g) return;
    // lower_bound(batch, i)
    int lo = 0, hi = n;
    while (lo < hi) { int m = (lo + hi) >> 1; if (batch[m] < i) lo = m + 1; else hi = m; }
    int a = lo;
    // lower_bound(batch, i+1)
    lo = 0; hi = n;
    while (lo < hi) { int m = (lo + hi) >> 1; if (batch[m] < i + 1) lo = m + 1; else hi = m; }
    counts[i] = lo - a;
}

// ---------------- aggregation + (1+eps)*h ----------------
// one wave (64 lanes) per node; lane l holds features [2l, 2l+1] as float2.
// 2-way unrolled neighbor accumulation + 4-batched index prefetch for MLP.
__global__ void agg_kernel(const float* __restrict__ h, const int* __restrict__ off,
                           const int* __restrict__ srcs, const float* __restrict__ eps_p,
                           float* __restrict__ pre, int n) {
    int wave = (int)((blockIdx.x * (size_t)blockDim.x + threadIdx.x) >> 6);
    int lane = threadIdx.x & 63;
    if (wave >= n) return;
    float eps1 = 1.0f + eps_p[0];
    const float2* hv = (const float2*)h;
    float2 self = hv[(size_t)wave * 64 + lane];
    float2 acc0 = make_float2(self.x * eps1, self.y * eps1);
    float2 acc1 = make_float2(0.f, 0.f);
    int j0 = off[wave], j1 = off[wave + 1];
    int j = j0;
    for (; j + 4 <= j1; j += 4) {
        int s0 = srcs[j + 0], s1 = srcs[j + 1], s2 = srcs[j + 2], s3 = srcs[j + 3];
        float2 v0 = hv[(size_t)s0 * 64 + lane];
        float2 v1 = hv[(size_t)s1 * 64 + lane];
        float2 v2 = hv[(size_t)s2 * 64 + lane];
        float2 v3 = hv[(size_t)s3 * 64 + lane];
        acc0.x += v0.x; acc0.y += v0.y;
        acc1.x += v1.x; acc1.y += v1.y;
        acc0.x += v2.x; acc0.y += v2.y;
        acc1.x += v3.x; acc1.y += v3.y;
    }
    for (; j < j1; ++j) {
        int s = srcs[j];
        float2 v = hv[(size_t)s * 64 + lane];
        acc0.x += v.x; acc0.y += v.y;
    }
    acc0.x += acc1.x; acc0.y += acc1.y;
    ((float2*)pre)[(size_t)wave * 64 + lane] = acc0;
}

// ---------------- fp32 GEMM: out[n,128] = A[n,128] @ W[128,128] + b, optional relu ----
// block: 256 threads, 64 rows x 128 cols tile. thread: 2 rows x 16 cols.
template <int RELU>
__global__ __launch_bounds__(256) void mlp_gemm_kernel(
    const float* __restrict__ A, const float* __restrict__ W,
    const float* __restrict__ b, float* __restrict__ out, int n) {
    __shared__ float Wl[128][128];
    int tid = threadIdx.x;
    {
        const float4* Wv = (const float4*)W;
        float4* Wlv = (float4*)&Wl[0][0];
        #pragma unroll
        for (int i = 0; i < 16; ++i) Wlv[tid + 256 * i] = Wv[tid + 256 * i];
    }
    __syncthreads();
    int col_group = tid & 7;       // 8 groups of 16 cols
    int row_pair  = tid >> 3;      // 32 pairs of rows
    int c0 = col_group * 16;
    long r0 = (long)blockIdx.x * 64 + row_pair * 2;
    bool v0 = r0 < n, v1 = (r0 + 1) < n;
    float acc0[16], acc1[16];
    #pragma unroll
    for (int i = 0; i < 16; ++i) { acc0[i] = 0.f; acc1[i] = 0.f; }
    const float4* a0p = (const float4*)(A + r0 * FEAT);
    const float4* a1p = (const float4*)(A + (r0 + 1) * FEAT);
    for (int k0 = 0; k0 < 32; ++k0) {
        float4 a0 = v0 ? a0p[k0] : make_float4(0.f, 0.f, 0.f, 0.f);
        float4 a1 = v1 ? a1p[k0] : make_float4(0.f, 0.f, 0.f, 0.f);
        #pragma unroll
        for (int kk = 0; kk < 4; ++kk) {
            float av0 = (&a0.x)[kk];
            float av1 = (&a1.x)[kk];
            int k = k0 * 4 + kk;
            #pragma unroll
            for (int c = 0; c < 16; ++c) {
                float w = Wl[k][c0 + c];
                acc0[c] += av0 * w;
                acc1[c] += av1 * w;
            }
        }
    }
    #pragma unroll
    for (int q = 0; q < 4; ++q) {
        float4 bv = ((const float4*)(b + c0))[q];
        if (v0) {
            float4 r;
            r.x = acc0[q*4+0] + bv.x; r.y = acc0[q*4+1] + bv.y;
            r.z = acc0[q*4+2] + bv.z; r.w = acc0[q*4+3] + bv.w;
            if (RELU) { r.x = fmaxf(r.x,0.f); r.y = fmaxf(r.y,0.f); r.z = fmaxf(r.z,0.f); r.w = fmaxf(r.w,0.f); }
            ((float4*)(out + r0 * FEAT + c0))[q] = r;
        }
        if (v1) {
            float4 r;
            r.x = acc1[q*4+0] + bv.x; r.y = acc1[q*4+1] + bv.y;
            r.z = acc1[q*4+2] + bv.z; r.w = acc1[q*4+3] + bv.w;
            if (RELU) { r.x = fmaxf(r.x,0.f); r.y = fmaxf(r.y,0.f); r.z = fmaxf(r.z,0.f); r.w = fmaxf(r.w,0.f); }
            ((float4*)(out + (r0 + 1) * FEAT + c0))[q] = r;
        }
    }
}

// ---------------- pooling: per-node dot with fc_w, atomic into per-graph sums ----
__global__ void pool_kernel(const float* __restrict__ h, const int* __restrict__ batch,
                            const float* __restrict__ fcw,
                            float* __restrict__ sums, int n) {
    int wave = (int)((blockIdx.x * (size_t)blockDim.x + threadIdx.x) >> 6);
    int lane = threadIdx.x & 63;
    if (wave >= n) return;
    float2 hv2 = ((const float2*)h)[(size_t)wave * 64 + lane];
    float2 wv = ((const float2*)fcw)[lane];
    float d = hv2.x * wv.x + hv2.y * wv.y;
    #pragma unroll
    for (int s = 32; s; s >>= 1) d += __shfl_down(d, s, 64);
    if (lane == 0) {
        int g = batch[wave];
        unsafeAtomicAdd(&sums[g], d);
    }
}

__global__ void final_kernel(const float* __restrict__ sums, const int* __restrict__ counts,
                             const float* __restrict__ fcb, float* __restrict__ out, int g) {
    int i = blockIdx.x * blockDim.x + threadIdx.x;
    if (i < g) out[i] = sums[i] / fmaxf((float)counts[i], 1.0f) + fcb[0];
}

static inline size_t align256(size_t x) { return (x + 255) & ~(size_t)255; }

extern "C" void kernel_launch(void* const* d_in, const int* in_sizes, int n_in,
                              void* d_out, int out_size, void* d_ws, size_t ws_size,
                              hipStream_t stream) {
    const float* x      = (const float*)d_in[0];
    const int*   ei     = (const int*)d_in[1];
    const int*   batch  = (const int*)d_in[2];
    const float* W1[3]  = {(const float*)d_in[3],  (const float*)d_in[8],  (const float*)d_in[13]};
    const float* b1[3]  = {(const float*)d_in[4],  (const float*)d_in[9],  (const float*)d_in[14]};
    const float* W2[3]  = {(const float*)d_in[5],  (const float*)d_in[10], (const float*)d_in[15]};
    const float* b2[3]  = {(const float*)d_in[6],  (const float*)d_in[11], (const float*)d_in[16]};
    const float* eps[3] = {(const float*)d_in[7],  (const float*)d_in[12], (const float*)d_in[17]};
    const float* fcw    = (const float*)d_in[18];
    const float* fcb    = (const float*)d_in[19];
    float* out = (float*)d_out;

    const int N = in_sizes[0] / FEAT;
    const int E = in_sizes[1] / 2;
    const int G = out_size;

    // workspace layout
    char* p = (char*)d_ws;
    int* off    = (int*)p;  p += align256((size_t)(N + 1) * 4);
    int* cursor = (int*)p;  p += align256((size_t)N * 4);
    int* srcs   = (int*)p;  p += align256((size_t)E * 4);
    float* sums = (float*)p; p += align256((size_t)G * 4);
    int* counts = (int*)p;  p += align256((size_t)G * 4);
    float* buf0 = (float*)p; p += align256((size_t)N * FEAT * 4);
    float* buf1 = (float*)p; p += align256((size_t)N * FEAT * 4);
    float* buf2 = (float*)p; p += align256((size_t)N * FEAT * 4);
    (void)ws_size; (void)n_in;

    const int* src = ei;        // edge_index[0]
    const int* dst = ei + E;    // edge_index[1]

    hipMemsetAsync(off, 0, (size_t)(N + 1) * 4, stream);
    hipMemsetAsync(sums, 0, (size_t)G * 4, stream);

    // CSR build (reused for all 3 layers)
    hist_kernel<<<(E + 255) / 256, 256, 0, stream>>>(dst, off, E);
    scan_kernel<<<1, 1024, 0, stream>>>(off, cursor, N);
    scatter_kernel<<<(E + 255) / 256, 256, 0, stream>>>(src, dst, cursor, srcs, E);
    counts_kernel<<<(G + 255) / 256, 256, 0, stream>>>(batch, counts, N, G);

    const int aggBlocks = (N + 3) / 4;       // 4 waves (nodes) per 256-thread block
    const int gemmBlocks = (N + 63) / 64;

    const float* h = x;
    float* pre = buf0;
    float* t   = buf1;
    float* hn  = buf2;
    for (int i = 0; i < 3; ++i) {
        agg_kernel<<<aggBlocks, 256, 0, stream>>>(h, off, srcs, eps[i], pre, N);
        mlp_gemm_kernel<1><<<gemmBlocks, 256, 0, stream>>>(pre, W1[i], b1[i], t, N);
        if (i < 2)
            mlp_gemm_kernel<1><<<gemmBlocks, 256, 0, stream>>>(t, W2[i], b2[i], hn, N);
        else
            mlp_gemm_kernel<0><<<gemmBlocks, 256, 0, stream>>>(t, W2[i], b2[i], hn, N);
        h = hn;  // buf2 always holds the current layer output
    }

    pool_kernel<<<aggBlocks, 256, 0, stream>>>(h, batch, fcw, sums, N);
    final_kernel<<<(G + 255) / 256, 256, 0, stream>>>(sums, counts, fcb, out, G);
}

// Round 3
// 773.269 us; speedup vs baseline: 1.1075x; 1.1075x over previous
//
#include <hip/hip_runtime.h>

// GIN regressor: 3x [segment-sum aggregation -> (1+eps)*x+agg -> Linear/ReLU/Linear]
// -> global mean pool by graph -> fc.
// CSR built once per call (hist -> 3-phase multi-block scan -> scatter), reused
// for all 3 layers; aggregation is gather-only (no float atomics). GEMMs are
// fp32 vector (no fp32 MFMA on CDNA4) with W staged in LDS.

#define FEAT 128

// ---------------- CSR build ----------------
__global__ void hist_kernel(const int* __restrict__ dst, int* __restrict__ deg, int E) {
    int e = blockIdx.x * blockDim.x + threadIdx.x;
    if (e < E) atomicAdd(&deg[dst[e]], 1);
}

// Phase A: blocksums[b] = sum(off[b*1024 .. b*1024+1023])
__global__ void block_sum_kernel(const int* __restrict__ off, int* __restrict__ bs, int n) {
    int b = blockIdx.x, t = threadIdx.x;   // 256 threads
    int base = b * 1024;
    int s = 0;
    #pragma unroll
    for (int i = 0; i < 4; ++i) {
        int idx = base + t + 256 * i;
        if (idx < n) s += off[idx];
    }
    #pragma unroll
    for (int d = 32; d; d >>= 1) s += __shfl_down(s, d, 64);
    __shared__ int ws[4];
    if ((t & 63) == 0) ws[t >> 6] = s;
    __syncthreads();
    if (t == 0) bs[b] = ws[0] + ws[1] + ws[2] + ws[3];
}

// Phase B: exclusive scan of bs[0..nb) (nb <= 1024), single block of 1024.
// Also writes off[n] = grand total.
__global__ void scan_blocksums_kernel(int* __restrict__ bs, int nb,
                                      int* __restrict__ off, int n) {
    __shared__ int l[1024];
    int t = threadIdx.x;
    int v = (t < nb) ? bs[t] : 0;
    l[t] = v;
    __syncthreads();
    for (int d = 1; d < 1024; d <<= 1) {
        int u = (t >= d) ? l[t - d] : 0;
        __syncthreads();
        l[t] += u;
        __syncthreads();
    }
    if (t < nb) bs[t] = (t == 0) ? 0 : l[t - 1];
    if (t == 1023) off[n] = l[1023];
}

// Phase C: per-block exclusive scan of its 1024-region + base; writes off & cursor.
__global__ __launch_bounds__(256) void block_scan_kernel(
    int* __restrict__ off, int* __restrict__ cursor,
    const int* __restrict__ bs, int n) {
    __shared__ int l[1024];
    __shared__ int part[256];
    int b = blockIdx.x, t = threadIdx.x;
    int base = b * 1024;
    #pragma unroll
    for (int i = 0; i < 4; ++i) {
        int idx = base + t + 256 * i;
        l[t + 256 * i] = (idx < n) ? off[idx] : 0;
    }
    __syncthreads();
    int v0 = l[4 * t], v1 = l[4 * t + 1], v2 = l[4 * t + 2], v3 = l[4 * t + 3];
    int p = v0 + v1 + v2 + v3;
    part[t] = p;
    __syncthreads();
    for (int d = 1; d < 256; d <<= 1) {
        int u = (t >= d) ? part[t - d] : 0;
        __syncthreads();
        part[t] += u;
        __syncthreads();
    }
    int ex = bs[b] + ((t == 0) ? 0 : part[t - 1]);
    int e0 = ex, e1 = ex + v0, e2 = e1 + v1, e3 = e2 + v2;
    int idx = base + 4 * t;
    if (idx + 3 < n) {
        ((int4*)(off + idx))[0]    = make_int4(e0, e1, e2, e3);
        ((int4*)(cursor + idx))[0] = make_int4(e0, e1, e2, e3);
    } else {
        if (idx + 0 < n) { off[idx + 0] = e0; cursor[idx + 0] = e0; }
        if (idx + 1 < n) { off[idx + 1] = e1; cursor[idx + 1] = e1; }
        if (idx + 2 < n) { off[idx + 2] = e2; cursor[idx + 2] = e2; }
    }
}

__global__ void scatter_kernel(const int* __restrict__ src, const int* __restrict__ dst,
                               int* __restrict__ cursor, int* __restrict__ srcs, int E) {
    int e = blockIdx.x * blockDim.x + threadIdx.x;
    if (e < E) {
        int d = dst[e];
        int p = atomicAdd(&cursor[d], 1);
        srcs[p] = src[e];
    }
}

// counts[g] = #nodes with batch == g (batch sorted ascending)
__global__ void counts_kernel(const int* __restrict__ batch, int* __restrict__ counts,
                              int n, int g) {
    int i = blockIdx.x * blockDim.x + threadIdx.x;
    if (i >= g) return;
    int lo = 0, hi = n;
    while (lo < hi) { int m = (lo + hi) >> 1; if (batch[m] < i) lo = m + 1; else hi = m; }
    int a = lo;
    lo = 0; hi = n;
    while (lo < hi) { int m = (lo + hi) >> 1; if (batch[m] < i + 1) lo = m + 1; else hi = m; }
    counts[i] = lo - a;
}

// ---------------- aggregation + (1+eps)*h ----------------
// one wave (64 lanes) per node; lane l holds features [2l, 2l+1] as float2.
__global__ void agg_kernel(const float* __restrict__ h, const int* __restrict__ off,
                           const int* __restrict__ srcs, const float* __restrict__ eps_p,
                           float* __restrict__ pre, int n) {
    int wave = (int)((blockIdx.x * (size_t)blockDim.x + threadIdx.x) >> 6);
    int lane = threadIdx.x & 63;
    if (wave >= n) return;
    float eps1 = 1.0f + eps_p[0];
    const float2* hv = (const float2*)h;
    float2 self = hv[(size_t)wave * 64 + lane];
    float2 acc0 = make_float2(self.x * eps1, self.y * eps1);
    float2 acc1 = make_float2(0.f, 0.f);
    int j0 = off[wave], j1 = off[wave + 1];
    int j = j0;
    for (; j + 4 <= j1; j += 4) {
        int s0 = srcs[j + 0], s1 = srcs[j + 1], s2 = srcs[j + 2], s3 = srcs[j + 3];
        float2 v0 = hv[(size_t)s0 * 64 + lane];
        float2 v1 = hv[(size_t)s1 * 64 + lane];
        float2 v2 = hv[(size_t)s2 * 64 + lane];
        float2 v3 = hv[(size_t)s3 * 64 + lane];
        acc0.x += v0.x; acc0.y += v0.y;
        acc1.x += v1.x; acc1.y += v1.y;
        acc0.x += v2.x; acc0.y += v2.y;
        acc1.x += v3.x; acc1.y += v3.y;
    }
    for (; j < j1; ++j) {
        int s = srcs[j];
        float2 v = hv[(size_t)s * 64 + lane];
        acc0.x += v.x; acc0.y += v.y;
    }
    acc0.x += acc1.x; acc0.y += acc1.y;
    ((float2*)pre)[(size_t)wave * 64 + lane] = acc0;
}

// ---------------- fp32 GEMM: out[n,128] = A[n,128] @ W[128,128] + b, optional relu ----
template <int RELU>
__global__ __launch_bounds__(256) void mlp_gemm_kernel(
    const float* __restrict__ A, const float* __restrict__ W,
    const float* __restrict__ b, float* __restrict__ out, int n) {
    __shared__ float Wl[128][128];
    int tid = threadIdx.x;
    {
        const float4* Wv = (const float4*)W;
        float4* Wlv = (float4*)&Wl[0][0];
        #pragma unroll
        for (int i = 0; i < 16; ++i) Wlv[tid + 256 * i] = Wv[tid + 256 * i];
    }
    __syncthreads();
    int col_group = tid & 7;
    int row_pair  = tid >> 3;
    int c0 = col_group * 16;
    long r0 = (long)blockIdx.x * 64 + row_pair * 2;
    bool v0 = r0 < n, v1 = (r0 + 1) < n;
    float acc0[16], acc1[16];
    #pragma unroll
    for (int i = 0; i < 16; ++i) { acc0[i] = 0.f; acc1[i] = 0.f; }
    const float4* a0p = (const float4*)(A + r0 * FEAT);
    const float4* a1p = (const float4*)(A + (r0 + 1) * FEAT);
    for (int k0 = 0; k0 < 32; ++k0) {
        float4 a0 = v0 ? a0p[k0] : make_float4(0.f, 0.f, 0.f, 0.f);
        float4 a1 = v1 ? a1p[k0] : make_float4(0.f, 0.f, 0.f, 0.f);
        #pragma unroll
        for (int kk = 0; kk < 4; ++kk) {
            float av0 = (&a0.x)[kk];
            float av1 = (&a1.x)[kk];
            int k = k0 * 4 + kk;
            #pragma unroll
            for (int c = 0; c < 16; ++c) {
                float w = Wl[k][c0 + c];
                acc0[c] += av0 * w;
                acc1[c] += av1 * w;
            }
        }
    }
    #pragma unroll
    for (int q = 0; q < 4; ++q) {
        float4 bv = ((const float4*)(b + c0))[q];
        if (v0) {
            float4 r;
            r.x = acc0[q*4+0] + bv.x; r.y = acc0[q*4+1] + bv.y;
            r.z = acc0[q*4+2] + bv.z; r.w = acc0[q*4+3] + bv.w;
            if (RELU) { r.x = fmaxf(r.x,0.f); r.y = fmaxf(r.y,0.f); r.z = fmaxf(r.z,0.f); r.w = fmaxf(r.w,0.f); }
            ((float4*)(out + r0 * FEAT + c0))[q] = r;
        }
        if (v1) {
            float4 r;
            r.x = acc1[q*4+0] + bv.x; r.y = acc1[q*4+1] + bv.y;
            r.z = acc1[q*4+2] + bv.z; r.w = acc1[q*4+3] + bv.w;
            if (RELU) { r.x = fmaxf(r.x,0.f); r.y = fmaxf(r.y,0.f); r.z = fmaxf(r.z,0.f); r.w = fmaxf(r.w,0.f); }
            ((float4*)(out + (r0 + 1) * FEAT + c0))[q] = r;
        }
    }
}

// ---------------- pooling: per-node dot with fc_w, atomic into per-graph sums ----
__global__ void pool_kernel(const float* __restrict__ h, const int* __restrict__ batch,
                            const float* __restrict__ fcw,
                            float* __restrict__ sums, int n) {
    int wave = (int)((blockIdx.x * (size_t)blockDim.x + threadIdx.x) >> 6);
    int lane = threadIdx.x & 63;
    if (wave >= n) return;
    float2 hv2 = ((const float2*)h)[(size_t)wave * 64 + lane];
    float2 wv = ((const float2*)fcw)[lane];
    float d = hv2.x * wv.x + hv2.y * wv.y;
    #pragma unroll
    for (int s = 32; s; s >>= 1) d += __shfl_down(d, s, 64);
    if (lane == 0) {
        int g = batch[wave];
        unsafeAtomicAdd(&sums[g], d);
    }
}

__global__ void final_kernel(const float* __restrict__ sums, const int* __restrict__ counts,
                             const float* __restrict__ fcb, float* __restrict__ out, int g) {
    int i = blockIdx.x * blockDim.x + threadIdx.x;
    if (i < g) out[i] = sums[i] / fmaxf((float)counts[i], 1.0f) + fcb[0];
}

static inline size_t align256(size_t x) { return (x + 255) & ~(size_t)255; }

extern "C" void kernel_launch(void* const* d_in, const int* in_sizes, int n_in,
                              void* d_out, int out_size, void* d_ws, size_t ws_size,
                              hipStream_t stream) {
    const float* x      = (const float*)d_in[0];
    const int*   ei     = (const int*)d_in[1];
    const int*   batch  = (const int*)d_in[2];
    const float* W1[3]  = {(const float*)d_in[3],  (const float*)d_in[8],  (const float*)d_in[13]};
    const float* b1[3]  = {(const float*)d_in[4],  (const float*)d_in[9],  (const float*)d_in[14]};
    const float* W2[3]  = {(const float*)d_in[5],  (const float*)d_in[10], (const float*)d_in[15]};
    const float* b2[3]  = {(const float*)d_in[6],  (const float*)d_in[11], (const float*)d_in[16]};
    const float* eps[3] = {(const float*)d_in[7],  (const float*)d_in[12], (const float*)d_in[17]};
    const float* fcw    = (const float*)d_in[18];
    const float* fcb    = (const float*)d_in[19];
    float* out = (float*)d_out;

    const int N = in_sizes[0] / FEAT;
    const int E = in_sizes[1] / 2;
    const int G = out_size;

    // workspace layout
    char* p = (char*)d_ws;
    int* off    = (int*)p;  p += align256((size_t)(N + 1) * 4);
    int* cursor = (int*)p;  p += align256((size_t)N * 4);
    int* srcs   = (int*)p;  p += align256((size_t)E * 4);
    int* bsums  = (int*)p;  p += align256((size_t)1024 * 4);
    float* sums = (float*)p; p += align256((size_t)G * 4);
    int* counts = (int*)p;  p += align256((size_t)G * 4);
    float* buf0 = (float*)p; p += align256((size_t)N * FEAT * 4);
    float* buf1 = (float*)p; p += align256((size_t)N * FEAT * 4);
    float* buf2 = (float*)p; p += align256((size_t)N * FEAT * 4);
    (void)ws_size; (void)n_in;

    const int* src = ei;        // edge_index[0]
    const int* dst = ei + E;    // edge_index[1]

    hipMemsetAsync(off, 0, (size_t)(N + 1) * 4, stream);
    hipMemsetAsync(sums, 0, (size_t)G * 4, stream);

    // CSR build (reused for all 3 layers)
    const int nb = (N + 1023) / 1024;   // scan blocks (<= 1024 supported)
    hist_kernel<<<(E + 255) / 256, 256, 0, stream>>>(dst, off, E);
    block_sum_kernel<<<nb, 256, 0, stream>>>(off, bsums, N);
    scan_blocksums_kernel<<<1, 1024, 0, stream>>>(bsums, nb, off, N);
    block_scan_kernel<<<nb, 256, 0, stream>>>(off, cursor, bsums, N);
    scatter_kernel<<<(E + 255) / 256, 256, 0, stream>>>(src, dst, cursor, srcs, E);
    counts_kernel<<<(G + 255) / 256, 256, 0, stream>>>(batch, counts, N, G);

    const int aggBlocks = (N + 3) / 4;       // 4 waves (nodes) per 256-thread block
    const int gemmBlocks = (N + 63) / 64;

    const float* h = x;
    float* pre = buf0;
    float* t   = buf1;
    float* hn  = buf2;
    for (int i = 0; i < 3; ++i) {
        agg_kernel<<<aggBlocks, 256, 0, stream>>>(h, off, srcs, eps[i], pre, N);
        mlp_gemm_kernel<1><<<gemmBlocks, 256, 0, stream>>>(pre, W1[i], b1[i], t, N);
        if (i < 2)
            mlp_gemm_kernel<1><<<gemmBlocks, 256, 0, stream>>>(t, W2[i], b2[i], hn, N);
        else
            mlp_gemm_kernel<0><<<gemmBlocks, 256, 0, stream>>>(t, W2[i], b2[i], hn, N);
        h = hn;  // buf2 always holds the current layer output
    }

    pool_kernel<<<aggBlocks, 256, 0, stream>>>(h, batch, fcw, sums, N);
    final_kernel<<<(G + 255) / 256, 256, 0, stream>>>(sums, counts, fcb, out, G);
}

// Round 4
// 647.426 us; speedup vs baseline: 1.3227x; 1.1944x over previous
//
#include <hip/hip_runtime.h>

// GIN regressor: 3x [segment-sum aggregation -> (1+eps)*x+agg -> Linear/ReLU/Linear]
// -> global mean pool by graph -> fc.
// CSR built once per call (hist -> 3-phase multi-block scan -> scatter), reused
// for all 3 layers; aggregation is gather-only (no float atomics). GEMMs are
// fp32 vector (no fp32 MFMA on CDNA4) with W staged in LDS.
// Last GEMM + pool + fc collapsed algebraically: out[g] = mean_g(t @ (W2@fcw)) + b2.fcw + fcb
// (everything after the last ReLU is linear), so layer-3's second GEMM is never run
// and pooling is a segmented dot with zero atomics (batch is sorted).

#define FEAT 128

// ---------------- CSR build ----------------
__global__ void hist_kernel(const int* __restrict__ dst, int* __restrict__ deg, int E) {
    int e = blockIdx.x * blockDim.x + threadIdx.x;
    if (e < E) atomicAdd(&deg[dst[e]], 1);
}

// Phase A: blocksums[b] = sum(off[b*1024 .. b*1024+1023])
__global__ void block_sum_kernel(const int* __restrict__ off, int* __restrict__ bs, int n) {
    int b = blockIdx.x, t = threadIdx.x;   // 256 threads
    int base = b * 1024;
    int s = 0;
    #pragma unroll
    for (int i = 0; i < 4; ++i) {
        int idx = base + t + 256 * i;
        if (idx < n) s += off[idx];
    }
    #pragma unroll
    for (int d = 32; d; d >>= 1) s += __shfl_down(s, d, 64);
    __shared__ int ws[4];
    if ((t & 63) == 0) ws[t >> 6] = s;
    __syncthreads();
    if (t == 0) bs[b] = ws[0] + ws[1] + ws[2] + ws[3];
}

// Phase B: exclusive scan of bs[0..nb) (nb <= 1024), single block of 1024.
// Also writes off[n] = grand total.
__global__ void scan_blocksums_kernel(int* __restrict__ bs, int nb,
                                      int* __restrict__ off, int n) {
    __shared__ int l[1024];
    int t = threadIdx.x;
    int v = (t < nb) ? bs[t] : 0;
    l[t] = v;
    __syncthreads();
    for (int d = 1; d < 1024; d <<= 1) {
        int u = (t >= d) ? l[t - d] : 0;
        __syncthreads();
        l[t] += u;
        __syncthreads();
    }
    if (t < nb) bs[t] = (t == 0) ? 0 : l[t - 1];
    if (t == 1023) off[n] = l[1023];
}

// Phase C: per-block exclusive scan of its 1024-region + base; writes off & cursor.
__global__ __launch_bounds__(256) void block_scan_kernel(
    int* __restrict__ off, int* __restrict__ cursor,
    const int* __restrict__ bs, int n) {
    __shared__ int l[1024];
    __shared__ int part[256];
    int b = blockIdx.x, t = threadIdx.x;
    int base = b * 1024;
    #pragma unroll
    for (int i = 0; i < 4; ++i) {
        int idx = base + t + 256 * i;
        l[t + 256 * i] = (idx < n) ? off[idx] : 0;
    }
    __syncthreads();
    int v0 = l[4 * t], v1 = l[4 * t + 1], v2 = l[4 * t + 2], v3 = l[4 * t + 3];
    int p = v0 + v1 + v2 + v3;
    part[t] = p;
    __syncthreads();
    for (int d = 1; d < 256; d <<= 1) {
        int u = (t >= d) ? part[t - d] : 0;
        __syncthreads();
        part[t] += u;
        __syncthreads();
    }
    int ex = bs[b] + ((t == 0) ? 0 : part[t - 1]);
    int e0 = ex, e1 = ex + v0, e2 = e1 + v1, e3 = e2 + v2;
    int idx = base + 4 * t;
    if (idx + 3 < n) {
        ((int4*)(off + idx))[0]    = make_int4(e0, e1, e2, e3);
        ((int4*)(cursor + idx))[0] = make_int4(e0, e1, e2, e3);
    } else {
        if (idx + 0 < n) { off[idx + 0] = e0; cursor[idx + 0] = e0; }
        if (idx + 1 < n) { off[idx + 1] = e1; cursor[idx + 1] = e1; }
        if (idx + 2 < n) { off[idx + 2] = e2; cursor[idx + 2] = e2; }
    }
}

__global__ void scatter_kernel(const int* __restrict__ src, const int* __restrict__ dst,
                               int* __restrict__ cursor, int* __restrict__ srcs, int E) {
    int e = blockIdx.x * blockDim.x + threadIdx.x;
    if (e < E) {
        int d = dst[e];
        int p = atomicAdd(&cursor[d], 1);
        srcs[p] = src[e];
    }
}

// gstart[g] = lower_bound(batch, g) for g in [0, G]; batch sorted => segments.
__global__ void gstart_kernel(const int* __restrict__ batch, int* __restrict__ gstart,
                              int n, int g) {
    int i = blockIdx.x * blockDim.x + threadIdx.x;
    if (i > g) return;
    int lo = 0, hi = n;
    while (lo < hi) { int m = (lo + hi) >> 1; if (batch[m] < i) lo = m + 1; else hi = m; }
    gstart[i] = lo;
}

// w_eff[k] = sum_j W2[k][j]*fcw[j]  (k<128); w_eff[128] = b2.fcw
__global__ void weff_kernel(const float* __restrict__ W2, const float* __restrict__ b2,
                            const float* __restrict__ fcw, float* __restrict__ weff) {
    int tid = threadIdx.x, lane = tid & 63, wave = tid >> 6;  // 256 threads
    float2 f2 = ((const float2*)fcw)[lane];
    for (int r = wave; r < 128; r += 4) {
        float2 w = ((const float2*)(W2 + r * FEAT))[lane];
        float d = w.x * f2.x + w.y * f2.y;
        #pragma unroll
        for (int s = 32; s; s >>= 1) d += __shfl_down(d, s, 64);
        if (lane == 0) weff[r] = d;
    }
    if (wave == 0) {
        float2 b = ((const float2*)b2)[lane];
        float d = b.x * f2.x + b.y * f2.y;
        #pragma unroll
        for (int s = 32; s; s >>= 1) d += __shfl_down(d, s, 64);
        if (lane == 0) weff[128] = d;
    }
}

// ---------------- aggregation + (1+eps)*h ----------------
// one wave (64 lanes) per node; lane l holds features [2l, 2l+1] as float2.
__global__ void agg_kernel(const float* __restrict__ h, const int* __restrict__ off,
                           const int* __restrict__ srcs, const float* __restrict__ eps_p,
                           float* __restrict__ pre, int n) {
    int wave = (int)((blockIdx.x * (size_t)blockDim.x + threadIdx.x) >> 6);
    int lane = threadIdx.x & 63;
    if (wave >= n) return;
    float eps1 = 1.0f + eps_p[0];
    const float2* hv = (const float2*)h;
    float2 self = hv[(size_t)wave * 64 + lane];
    float2 acc0 = make_float2(self.x * eps1, self.y * eps1);
    float2 acc1 = make_float2(0.f, 0.f);
    int j0 = off[wave], j1 = off[wave + 1];
    int j = j0;
    for (; j + 4 <= j1; j += 4) {
        int s0 = srcs[j + 0], s1 = srcs[j + 1], s2 = srcs[j + 2], s3 = srcs[j + 3];
        float2 v0 = hv[(size_t)s0 * 64 + lane];
        float2 v1 = hv[(size_t)s1 * 64 + lane];
        float2 v2 = hv[(size_t)s2 * 64 + lane];
        float2 v3 = hv[(size_t)s3 * 64 + lane];
        acc0.x += v0.x; acc0.y += v0.y;
        acc1.x += v1.x; acc1.y += v1.y;
        acc0.x += v2.x; acc0.y += v2.y;
        acc1.x += v3.x; acc1.y += v3.y;
    }
    for (; j < j1; ++j) {
        int s = srcs[j];
        float2 v = hv[(size_t)s * 64 + lane];
        acc0.x += v.x; acc0.y += v.y;
    }
    acc0.x += acc1.x; acc0.y += acc1.y;
    ((float2*)pre)[(size_t)wave * 64 + lane] = acc0;
}

// ---------------- fp32 GEMM: out[n,128] = A[n,128] @ W[128,128] + b, optional relu ----
template <int RELU>
__global__ __launch_bounds__(256) void mlp_gemm_kernel(
    const float* __restrict__ A, const float* __restrict__ W,
    const float* __restrict__ b, float* __restrict__ out, int n) {
    __shared__ float Wl[128][128];
    int tid = threadIdx.x;
    {
        const float4* Wv = (const float4*)W;
        float4* Wlv = (float4*)&Wl[0][0];
        #pragma unroll
        for (int i = 0; i < 16; ++i) Wlv[tid + 256 * i] = Wv[tid + 256 * i];
    }
    __syncthreads();
    int col_group = tid & 7;
    int row_pair  = tid >> 3;
    int c0 = col_group * 16;
    long r0 = (long)blockIdx.x * 64 + row_pair * 2;
    bool v0 = r0 < n, v1 = (r0 + 1) < n;
    float acc0[16], acc1[16];
    #pragma unroll
    for (int i = 0; i < 16; ++i) { acc0[i] = 0.f; acc1[i] = 0.f; }
    const float4* a0p = (const float4*)(A + r0 * FEAT);
    const float4* a1p = (const float4*)(A + (r0 + 1) * FEAT);
    for (int k0 = 0; k0 < 32; ++k0) {
        float4 a0 = v0 ? a0p[k0] : make_float4(0.f, 0.f, 0.f, 0.f);
        float4 a1 = v1 ? a1p[k0] : make_float4(0.f, 0.f, 0.f, 0.f);
        #pragma unroll
        for (int kk = 0; kk < 4; ++kk) {
            float av0 = (&a0.x)[kk];
            float av1 = (&a1.x)[kk];
            int k = k0 * 4 + kk;
            #pragma unroll
            for (int c = 0; c < 16; ++c) {
                float w = Wl[k][c0 + c];
                acc0[c] += av0 * w;
                acc1[c] += av1 * w;
            }
        }
    }
    #pragma unroll
    for (int q = 0; q < 4; ++q) {
        float4 bv = ((const float4*)(b + c0))[q];
        if (v0) {
            float4 r;
            r.x = acc0[q*4+0] + bv.x; r.y = acc0[q*4+1] + bv.y;
            r.z = acc0[q*4+2] + bv.z; r.w = acc0[q*4+3] + bv.w;
            if (RELU) { r.x = fmaxf(r.x,0.f); r.y = fmaxf(r.y,0.f); r.z = fmaxf(r.z,0.f); r.w = fmaxf(r.w,0.f); }
            ((float4*)(out + r0 * FEAT + c0))[q] = r;
        }
        if (v1) {
            float4 r;
            r.x = acc1[q*4+0] + bv.x; r.y = acc1[q*4+1] + bv.y;
            r.z = acc1[q*4+2] + bv.z; r.w = acc1[q*4+3] + bv.w;
            if (RELU) { r.x = fmaxf(r.x,0.f); r.y = fmaxf(r.y,0.f); r.z = fmaxf(r.z,0.f); r.w = fmaxf(r.w,0.f); }
            ((float4*)(out + (r0 + 1) * FEAT + c0))[q] = r;
        }
    }
}

// ---------------- pooling: one block per graph, segmented dot t . w_eff --------
// out[g] = (sum_{n in g} t[n].w_eff)/cnt + w_eff[128] + fcb  (no atomics; batch sorted)
__global__ __launch_bounds__(256) void pool_kernel(const float* __restrict__ t,
    const int* __restrict__ gstart, const float* __restrict__ weff,
    const float* __restrict__ fcb, float* __restrict__ out, int G) {
    int g = blockIdx.x;
    int tid = threadIdx.x, lane = tid & 63, wave = tid >> 6;
    int s0 = gstart[g], s1 = gstart[g + 1];
    int cnt = s1 - s0;
    float2 w2 = ((const float2*)weff)[lane];
    float acc = 0.f;
    for (int nidx = s0 + wave; nidx < s1; nidx += 4) {
        float2 v = ((const float2*)t)[(size_t)nidx * 64 + lane];
        acc += v.x * w2.x + v.y * w2.y;
    }
    #pragma unroll
    for (int d = 32; d; d >>= 1) acc += __shfl_down(acc, d, 64);
    __shared__ float ws[4];
    if (lane == 0) ws[wave] = acc;
    __syncthreads();
    if (tid == 0) {
        float total = ws[0] + ws[1] + ws[2] + ws[3];
        out[g] = (cnt > 0) ? total / (float)cnt + weff[128] + fcb[0] : fcb[0];
    }
}

static inline size_t align256(size_t x) { return (x + 255) & ~(size_t)255; }

extern "C" void kernel_launch(void* const* d_in, const int* in_sizes, int n_in,
                              void* d_out, int out_size, void* d_ws, size_t ws_size,
                              hipStream_t stream) {
    const float* x      = (const float*)d_in[0];
    const int*   ei     = (const int*)d_in[1];
    const int*   batch  = (const int*)d_in[2];
    const float* W1[3]  = {(const float*)d_in[3],  (const float*)d_in[8],  (const float*)d_in[13]};
    const float* b1[3]  = {(const float*)d_in[4],  (const float*)d_in[9],  (const float*)d_in[14]};
    const float* W2[3]  = {(const float*)d_in[5],  (const float*)d_in[10], (const float*)d_in[15]};
    const float* b2[3]  = {(const float*)d_in[6],  (const float*)d_in[11], (const float*)d_in[16]};
    const float* eps[3] = {(const float*)d_in[7],  (const float*)d_in[12], (const float*)d_in[17]};
    const float* fcw    = (const float*)d_in[18];
    const float* fcb    = (const float*)d_in[19];
    float* out = (float*)d_out;

    const int N = in_sizes[0] / FEAT;
    const int E = in_sizes[1] / 2;
    const int G = out_size;

    // workspace layout
    char* p = (char*)d_ws;
    int* off    = (int*)p;  p += align256((size_t)(N + 1) * 4);
    int* cursor = (int*)p;  p += align256((size_t)N * 4);
    int* srcs   = (int*)p;  p += align256((size_t)E * 4);
    int* bsums  = (int*)p;  p += align256((size_t)1024 * 4);
    int* gstart = (int*)p;  p += align256((size_t)(G + 1) * 4);
    float* weff = (float*)p; p += align256((size_t)256 * 4);
    float* buf0 = (float*)p; p += align256((size_t)N * FEAT * 4);
    float* buf1 = (float*)p; p += align256((size_t)N * FEAT * 4);
    float* buf2 = (float*)p; p += align256((size_t)N * FEAT * 4);
    (void)ws_size; (void)n_in;

    const int* src = ei;        // edge_index[0]
    const int* dst = ei + E;    // edge_index[1]

    hipMemsetAsync(off, 0, (size_t)(N + 1) * 4, stream);

    // CSR build (reused for all 3 layers)
    const int nb = (N + 1023) / 1024;   // scan blocks (<= 1024 supported)
    hist_kernel<<<(E + 255) / 256, 256, 0, stream>>>(dst, off, E);
    block_sum_kernel<<<nb, 256, 0, stream>>>(off, bsums, N);
    scan_blocksums_kernel<<<1, 1024, 0, stream>>>(bsums, nb, off, N);
    block_scan_kernel<<<nb, 256, 0, stream>>>(off, cursor, bsums, N);
    scatter_kernel<<<(E + 255) / 256, 256, 0, stream>>>(src, dst, cursor, srcs, E);
    gstart_kernel<<<(G + 256) / 256, 256, 0, stream>>>(batch, gstart, N, G);
    weff_kernel<<<1, 256, 0, stream>>>(W2[2], b2[2], fcw, weff);

    const int aggBlocks = (N + 3) / 4;       // 4 waves (nodes) per 256-thread block
    const int gemmBlocks = (N + 63) / 64;

    // layer 0: x -> buf2 ; layer 1: buf2 -> buf2 ; layer 2: agg+gemm1 only -> buf1
    const float* h = x;
    for (int i = 0; i < 3; ++i) {
        agg_kernel<<<aggBlocks, 256, 0, stream>>>(h, off, srcs, eps[i], buf0, N);
        mlp_gemm_kernel<1><<<gemmBlocks, 256, 0, stream>>>(buf0, W1[i], b1[i], buf1, N);
        if (i < 2) {
            mlp_gemm_kernel<1><<<gemmBlocks, 256, 0, stream>>>(buf1, W2[i], b2[i], buf2, N);
            h = buf2;
        }
    }
    // final: segmented dot of buf1 (= relu(pre@W1_2+b1_2)) with w_eff
    pool_kernel<<<G, 256, 0, stream>>>(buf1, gstart, weff, fcb, out, G);
}

// Round 5
// 457.070 us; speedup vs baseline: 1.8736x; 1.4165x over previous
//
#include <hip/hip_runtime.h>

// GIN regressor: 3x [segment-sum aggregation -> (1+eps)*x+agg -> Linear/ReLU/Linear]
// -> global mean pool -> fc.
// CSR built once per call; aggregation gather-only in fp32 (h table fp32).
// The 5 surviving GEMMs (layer2's 2nd GEMM is algebraically folded into the pool)
// run on bf16 MFMA (16x16x32, fp32 accum). Weights are pre-transposed/cast/
// XOR-swizzled once per call (wprep) so per-block LDS staging is a linear copy
// and b-frag ds_read_b128 is ~conflict-free (T2-style chunk^(col&7) swizzle).

#define FEAT 128

typedef short  bf16x8 __attribute__((ext_vector_type(8)));
typedef float  f32x4  __attribute__((ext_vector_type(4)));

__device__ inline unsigned short f2bf(float f) {  // round-to-nearest-even fp32->bf16
    unsigned int u = __float_as_uint(f);
    u = (u + 0x7FFFu + ((u >> 16) & 1u)) >> 16;
    return (unsigned short)u;
}

// ---------------- CSR build ----------------
__global__ void hist_kernel(const int* __restrict__ dst, int* __restrict__ deg, int E) {
    int e = blockIdx.x * blockDim.x + threadIdx.x;
    if (e < E) atomicAdd(&deg[dst[e]], 1);
}

__global__ void block_sum_kernel(const int* __restrict__ off, int* __restrict__ bs, int n) {
    int b = blockIdx.x, t = threadIdx.x;   // 256 threads
    int base = b * 1024;
    int s = 0;
    #pragma unroll
    for (int i = 0; i < 4; ++i) {
        int idx = base + t + 256 * i;
        if (idx < n) s += off[idx];
    }
    #pragma unroll
    for (int d = 32; d; d >>= 1) s += __shfl_down(s, d, 64);
    __shared__ int ws[4];
    if ((t & 63) == 0) ws[t >> 6] = s;
    __syncthreads();
    if (t == 0) bs[b] = ws[0] + ws[1] + ws[2] + ws[3];
}

__global__ void scan_blocksums_kernel(int* __restrict__ bs, int nb,
                                      int* __restrict__ off, int n) {
    __shared__ int l[1024];
    int t = threadIdx.x;
    int v = (t < nb) ? bs[t] : 0;
    l[t] = v;
    __syncthreads();
    for (int d = 1; d < 1024; d <<= 1) {
        int u = (t >= d) ? l[t - d] : 0;
        __syncthreads();
        l[t] += u;
        __syncthreads();
    }
    if (t < nb) bs[t] = (t == 0) ? 0 : l[t - 1];
    if (t == 1023) off[n] = l[1023];
}

__global__ __launch_bounds__(256) void block_scan_kernel(
    int* __restrict__ off, int* __restrict__ cursor,
    const int* __restrict__ bs, int n) {
    __shared__ int l[1024];
    __shared__ int part[256];
    int b = blockIdx.x, t = threadIdx.x;
    int base = b * 1024;
    #pragma unroll
    for (int i = 0; i < 4; ++i) {
        int idx = base + t + 256 * i;
        l[t + 256 * i] = (idx < n) ? off[idx] : 0;
    }
    __syncthreads();
    int v0 = l[4 * t], v1 = l[4 * t + 1], v2 = l[4 * t + 2], v3 = l[4 * t + 3];
    int p = v0 + v1 + v2 + v3;
    part[t] = p;
    __syncthreads();
    for (int d = 1; d < 256; d <<= 1) {
        int u = (t >= d) ? part[t - d] : 0;
        __syncthreads();
        part[t] += u;
        __syncthreads();
    }
    int ex = bs[b] + ((t == 0) ? 0 : part[t - 1]);
    int e0 = ex, e1 = ex + v0, e2 = e1 + v1, e3 = e2 + v2;
    int idx = base + 4 * t;
    if (idx + 3 < n) {
        ((int4*)(off + idx))[0]    = make_int4(e0, e1, e2, e3);
        ((int4*)(cursor + idx))[0] = make_int4(e0, e1, e2, e3);
    } else {
        if (idx + 0 < n) { off[idx + 0] = e0; cursor[idx + 0] = e0; }
        if (idx + 1 < n) { off[idx + 1] = e1; cursor[idx + 1] = e1; }
        if (idx + 2 < n) { off[idx + 2] = e2; cursor[idx + 2] = e2; }
    }
}

__global__ void scatter_kernel(const int* __restrict__ src, const int* __restrict__ dst,
                               int* __restrict__ cursor, int* __restrict__ srcs, int E) {
    int e = blockIdx.x * blockDim.x + threadIdx.x;
    if (e < E) {
        int d = dst[e];
        int p = atomicAdd(&cursor[d], 1);
        srcs[p] = src[e];
    }
}

// gstart[g] = lower_bound(batch, g) for g in [0, G]
__global__ void gstart_kernel(const int* __restrict__ batch, int* __restrict__ gstart,
                              int n, int g) {
    int i = blockIdx.x * blockDim.x + threadIdx.x;
    if (i > g) return;
    int lo = 0, hi = n;
    while (lo < hi) { int m = (lo + hi) >> 1; if (batch[m] < i) lo = m + 1; else hi = m; }
    gstart[i] = lo;
}

// w_eff[k] = sum_j W2[k][j]*fcw[j]; w_eff[128] = b2.fcw
__global__ void weff_kernel(const float* __restrict__ W2, const float* __restrict__ b2,
                            const float* __restrict__ fcw, float* __restrict__ weff) {
    int tid = threadIdx.x, lane = tid & 63, wave = tid >> 6;
    float2 f2 = ((const float2*)fcw)[lane];
    for (int r = wave; r < 128; r += 4) {
        float2 w = ((const float2*)(W2 + r * FEAT))[lane];
        float d = w.x * f2.x + w.y * f2.y;
        #pragma unroll
        for (int s = 32; s; s >>= 1) d += __shfl_down(d, s, 64);
        if (lane == 0) weff[r] = d;
    }
    if (wave == 0) {
        float2 b = ((const float2*)b2)[lane];
        float d = b.x * f2.x + b.y * f2.y;
        #pragma unroll
        for (int s = 32; s; s >>= 1) d += __shfl_down(d, s, 64);
        if (lane == 0) weff[128] = d;
    }
}

// ---- weight prep: Wswz[mat][c][chunk^(c&7)][j] = bf16(W[8*chunk+j][c]) ----
// 5 matrices x 128 cols x 16 chunks; one task per (mat,c,chunk).
__global__ void wprep_kernel(const float* __restrict__ W0, const float* __restrict__ W1,
                             const float* __restrict__ W2, const float* __restrict__ W3,
                             const float* __restrict__ W4, unsigned short* __restrict__ Wswz) {
    int gid = blockIdx.x * 256 + threadIdx.x;
    if (gid >= 5 * 2048) return;
    int mat = gid >> 11;
    int task = gid & 2047;
    int c = task >> 4, m = task & 15;
    const float* W = (mat == 0) ? W0 : (mat == 1) ? W1 : (mat == 2) ? W2 : (mat == 3) ? W3 : W4;
    unsigned short* dst = Wswz + mat * 16384 + c * 128 + ((m ^ (c & 7)) << 3);
    #pragma unroll
    for (int j = 0; j < 8; ++j) dst[j] = f2bf(W[(8 * m + j) * FEAT + c]);
}

// ---------------- aggregation + (1+eps)*h -> bf16 pre ----------------
// one wave per node; lane l holds features [2l, 2l+1] as float2 (fp32 gather).
__global__ void agg_kernel(const float* __restrict__ h, const int* __restrict__ off,
                           const int* __restrict__ srcs, const float* __restrict__ eps_p,
                           unsigned int* __restrict__ pre_bf, int n) {
    int wave = (int)((blockIdx.x * (size_t)blockDim.x + threadIdx.x) >> 6);
    int lane = threadIdx.x & 63;
    if (wave >= n) return;
    float eps1 = 1.0f + eps_p[0];
    const float2* hv = (const float2*)h;
    float2 self = hv[(size_t)wave * 64 + lane];
    float2 acc0 = make_float2(self.x * eps1, self.y * eps1);
    float2 acc1 = make_float2(0.f, 0.f);
    int j0 = off[wave], j1 = off[wave + 1];
    int j = j0;
    for (; j + 4 <= j1; j += 4) {
        int s0 = srcs[j + 0], s1 = srcs[j + 1], s2 = srcs[j + 2], s3 = srcs[j + 3];
        float2 v0 = hv[(size_t)s0 * 64 + lane];
        float2 v1 = hv[(size_t)s1 * 64 + lane];
        float2 v2 = hv[(size_t)s2 * 64 + lane];
        float2 v3 = hv[(size_t)s3 * 64 + lane];
        acc0.x += v0.x; acc0.y += v0.y;
        acc1.x += v1.x; acc1.y += v1.y;
        acc0.x += v2.x; acc0.y += v2.y;
        acc1.x += v3.x; acc1.y += v3.y;
    }
    for (; j < j1; ++j) {
        int s = srcs[j];
        float2 v = hv[(size_t)s * 64 + lane];
        acc0.x += v.x; acc0.y += v.y;
    }
    acc0.x += acc1.x; acc0.y += acc1.y;
    unsigned int packed = (unsigned int)f2bf(acc0.x) | ((unsigned int)f2bf(acc0.y) << 16);
    pre_bf[(size_t)wave * 64 + lane] = packed;
}

// ---------------- bf16 MFMA GEMM: out[n,128] = A[n,128] @ W[128,128] + b ----
// A bf16 row-major; W pre-swizzled bf16 (Wswz layout). 256 threads, 64 rows/block,
// wave w owns rows [w*16, w*16+16), all 128 cols (8 N-tiles), K-loop 4x32.
template <int RELU, int OUT_BF16>
__global__ __launch_bounds__(256) void mfma_mlp_kernel(
    const unsigned short* __restrict__ A, const unsigned short* __restrict__ Wswz,
    const float* __restrict__ bias, void* __restrict__ outp, int n) {
    __shared__ int4 Wl4[2048];   // 32KB: swizzled W
    int tid = threadIdx.x;
    const int4* ws4 = (const int4*)Wswz;
    #pragma unroll
    for (int i = 0; i < 8; ++i) Wl4[i * 256 + tid] = ws4[i * 256 + tid];
    __syncthreads();
    const unsigned short* Wl = (const unsigned short*)Wl4;

    int lane = tid & 63, wave = tid >> 6;
    int q = lane >> 4, c15 = lane & 15;
    int r0 = blockIdx.x * 64 + wave * 16;
    int arow = r0 + c15;
    bool rv = arow < n;
    const bf16x8* ap = (const bf16x8*)(A + (size_t)arow * FEAT + q * 8);

    f32x4 zf = {0.f, 0.f, 0.f, 0.f};
    f32x4 acc[8];
    #pragma unroll
    for (int i = 0; i < 8; ++i) acc[i] = zf;
    bf16x8 zero8 = {0, 0, 0, 0, 0, 0, 0, 0};

    #pragma unroll
    for (int k0 = 0; k0 < 4; ++k0) {            // k base = 32*k0
        bf16x8 a = rv ? ap[k0 * 4] : zero8;     // A[arow][32k0 + 8q .. +7]
        int m = k0 * 4 + q;                     // chunk index
        #pragma unroll
        for (int nt = 0; nt < 8; ++nt) {
            int col = nt * 16 + c15;
            bf16x8 b = *(const bf16x8*)&Wl[col * 128 + ((m ^ (col & 7)) << 3)];
            acc[nt] = __builtin_amdgcn_mfma_f32_16x16x32_bf16(a, b, acc[nt], 0, 0, 0);
        }
    }

    int orow0 = r0 + q * 4;
    #pragma unroll
    for (int nt = 0; nt < 8; ++nt) {
        int col = nt * 16 + c15;
        float bv = bias[col];
        #pragma unroll
        for (int r = 0; r < 4; ++r) {
            int ro = orow0 + r;
            if (ro < n) {
                float v = acc[nt][r] + bv;
                if (RELU) v = fmaxf(v, 0.f);
                if (OUT_BF16) ((unsigned short*)outp)[(size_t)ro * FEAT + col] = f2bf(v);
                else          ((float*)outp)[(size_t)ro * FEAT + col] = v;
            }
        }
    }
}

// ---------------- pooling: one block per graph, segmented dot t . w_eff --------
__global__ __launch_bounds__(256) void pool_kernel(const float* __restrict__ t,
    const int* __restrict__ gstart, const float* __restrict__ weff,
    const float* __restrict__ fcb, float* __restrict__ out, int G) {
    int g = blockIdx.x;
    int tid = threadIdx.x, lane = tid & 63, wave = tid >> 6;
    int s0 = gstart[g], s1 = gstart[g + 1];
    int cnt = s1 - s0;
    float2 w2 = ((const float2*)weff)[lane];
    float acc = 0.f;
    for (int nidx = s0 + wave; nidx < s1; nidx += 4) {
        float2 v = ((const float2*)t)[(size_t)nidx * 64 + lane];
        acc += v.x * w2.x + v.y * w2.y;
    }
    #pragma unroll
    for (int d = 32; d; d >>= 1) acc += __shfl_down(acc, d, 64);
    __shared__ float ws[4];
    if (lane == 0) ws[wave] = acc;
    __syncthreads();
    if (tid == 0) {
        float total = ws[0] + ws[1] + ws[2] + ws[3];
        out[g] = (cnt > 0) ? total / (float)cnt + weff[128] + fcb[0] : fcb[0];
    }
}

static inline size_t align256(size_t x) { return (x + 255) & ~(size_t)255; }

extern "C" void kernel_launch(void* const* d_in, const int* in_sizes, int n_in,
                              void* d_out, int out_size, void* d_ws, size_t ws_size,
                              hipStream_t stream) {
    const float* x      = (const float*)d_in[0];
    const int*   ei     = (const int*)d_in[1];
    const int*   batch  = (const int*)d_in[2];
    const float* W1[3]  = {(const float*)d_in[3],  (const float*)d_in[8],  (const float*)d_in[13]};
    const float* b1[3]  = {(const float*)d_in[4],  (const float*)d_in[9],  (const float*)d_in[14]};
    const float* W2[3]  = {(const float*)d_in[5],  (const float*)d_in[10], (const float*)d_in[15]};
    const float* b2[3]  = {(const float*)d_in[6],  (const float*)d_in[11], (const float*)d_in[16]};
    const float* eps[3] = {(const float*)d_in[7],  (const float*)d_in[12], (const float*)d_in[17]};
    const float* fcw    = (const float*)d_in[18];
    const float* fcb    = (const float*)d_in[19];
    float* out = (float*)d_out;

    const int N = in_sizes[0] / FEAT;
    const int E = in_sizes[1] / 2;
    const int G = out_size;

    // workspace layout
    char* p = (char*)d_ws;
    int* off    = (int*)p;  p += align256((size_t)(N + 1) * 4);
    int* cursor = (int*)p;  p += align256((size_t)N * 4);
    int* srcs   = (int*)p;  p += align256((size_t)E * 4);
    int* bsums  = (int*)p;  p += align256((size_t)1024 * 4);
    int* gstart = (int*)p;  p += align256((size_t)(G + 1) * 4);
    float* weff = (float*)p; p += align256((size_t)256 * 4);
    unsigned short* Wswz = (unsigned short*)p; p += align256((size_t)5 * 16384 * 2);
    unsigned int* pre_bf = (unsigned int*)p;   p += align256((size_t)N * 64 * 4);  // bf16 [N][128]
    unsigned int* t_bf   = (unsigned int*)p;   p += align256((size_t)N * 64 * 4);  // bf16 [N][128]
    float* buf1 = (float*)p; p += align256((size_t)N * FEAT * 4);  // fp32 t (layer 2)
    float* buf2 = (float*)p; p += align256((size_t)N * FEAT * 4);  // fp32 h
    (void)ws_size; (void)n_in;

    const int* src = ei;        // edge_index[0]
    const int* dst = ei + E;    // edge_index[1]

    hipMemsetAsync(off, 0, (size_t)(N + 1) * 4, stream);

    // CSR build (reused for all 3 layers) + weight prep
    const int nb = (N + 1023) / 1024;
    hist_kernel<<<(E + 255) / 256, 256, 0, stream>>>(dst, off, E);
    block_sum_kernel<<<nb, 256, 0, stream>>>(off, bsums, N);
    scan_blocksums_kernel<<<1, 1024, 0, stream>>>(bsums, nb, off, N);
    block_scan_kernel<<<nb, 256, 0, stream>>>(off, cursor, bsums, N);
    scatter_kernel<<<(E + 255) / 256, 256, 0, stream>>>(src, dst, cursor, srcs, E);
    gstart_kernel<<<(G + 256) / 256, 256, 0, stream>>>(batch, gstart, N, G);
    weff_kernel<<<1, 256, 0, stream>>>(W2[2], b2[2], fcw, weff);
    wprep_kernel<<<40, 256, 0, stream>>>(W1[0], W2[0], W1[1], W2[1], W1[2], Wswz);

    const int aggBlocks  = (N + 3) / 4;
    const int gemmBlocks = (N + 63) / 64;
    const unsigned short* Wz[5] = {Wswz, Wswz + 16384, Wswz + 2 * 16384,
                                   Wswz + 3 * 16384, Wswz + 4 * 16384};

    // layers 0,1: agg -> gemm1(bf16 out) -> gemm2(fp32 h out, inter-layer relu)
    const float* h = x;
    for (int i = 0; i < 2; ++i) {
        agg_kernel<<<aggBlocks, 256, 0, stream>>>(h, off, srcs, eps[i], pre_bf, N);
        mfma_mlp_kernel<1, 1><<<gemmBlocks, 256, 0, stream>>>(
            (const unsigned short*)pre_bf, Wz[2 * i], b1[i], (void*)t_bf, N);
        mfma_mlp_kernel<1, 0><<<gemmBlocks, 256, 0, stream>>>(
            (const unsigned short*)t_bf, Wz[2 * i + 1], b2[i], (void*)buf2, N);
        h = buf2;
    }
    // layer 2: agg -> gemm1 (fp32 t out); W2_2+fc folded into pool via weff
    agg_kernel<<<aggBlocks, 256, 0, stream>>>(h, off, srcs, eps[2], pre_bf, N);
    mfma_mlp_kernel<1, 0><<<gemmBlocks, 256, 0, stream>>>(
        (const unsigned short*)pre_bf, Wz[4], b1[2], (void*)buf1, N);

    pool_kernel<<<G, 256, 0, stream>>>(buf1, gstart, weff, fcb, out, G);
}

// Round 6
// 409.196 us; speedup vs baseline: 2.0928x; 1.1170x over previous
//
#include <hip/hip_runtime.h>

// GIN regressor: 3x [segment-sum aggregation -> (1+eps)*x+agg -> Linear/ReLU/Linear]
// -> global mean pool -> fc.
// CSR built once per call; aggregation is gather-only over BF16 feature tables
// (x cast once; inter-layer h written as bf16 by the GEMM epilogue) -> half the
// gather traffic vs fp32. The 5 surviving GEMMs (layer2's 2nd GEMM folded into
// the pool) run on bf16 MFMA (16x16x32, fp32 accum) with pre-swizzled weights.

#define FEAT 128

typedef short  bf16x8 __attribute__((ext_vector_type(8)));
typedef float  f32x4  __attribute__((ext_vector_type(4)));

__device__ inline unsigned short f2bf(float f) {  // round-to-nearest-even fp32->bf16
    unsigned int u = __float_as_uint(f);
    u = (u + 0x7FFFu + ((u >> 16) & 1u)) >> 16;
    return (unsigned short)u;
}
__device__ inline float2 bfpair(unsigned int u) { // packed 2x bf16 -> 2x fp32
    float2 r;
    r.x = __uint_as_float(u << 16);
    r.y = __uint_as_float(u & 0xffff0000u);
    return r;
}

// ---------------- CSR build ----------------
__global__ void hist_kernel(const int* __restrict__ dst, int* __restrict__ deg, int E) {
    int e = blockIdx.x * blockDim.x + threadIdx.x;
    if (e < E) atomicAdd(&deg[dst[e]], 1);
}

__global__ void block_sum_kernel(const int* __restrict__ off, int* __restrict__ bs, int n) {
    int b = blockIdx.x, t = threadIdx.x;   // 256 threads
    int base = b * 1024;
    int s = 0;
    #pragma unroll
    for (int i = 0; i < 4; ++i) {
        int idx = base + t + 256 * i;
        if (idx < n) s += off[idx];
    }
    #pragma unroll
    for (int d = 32; d; d >>= 1) s += __shfl_down(s, d, 64);
    __shared__ int ws[4];
    if ((t & 63) == 0) ws[t >> 6] = s;
    __syncthreads();
    if (t == 0) bs[b] = ws[0] + ws[1] + ws[2] + ws[3];
}

__global__ void scan_blocksums_kernel(int* __restrict__ bs, int nb,
                                      int* __restrict__ off, int n) {
    __shared__ int l[1024];
    int t = threadIdx.x;
    int v = (t < nb) ? bs[t] : 0;
    l[t] = v;
    __syncthreads();
    for (int d = 1; d < 1024; d <<= 1) {
        int u = (t >= d) ? l[t - d] : 0;
        __syncthreads();
        l[t] += u;
        __syncthreads();
    }
    if (t < nb) bs[t] = (t == 0) ? 0 : l[t - 1];
    if (t == 1023) off[n] = l[1023];
}

__global__ __launch_bounds__(256) void block_scan_kernel(
    int* __restrict__ off, int* __restrict__ cursor,
    const int* __restrict__ bs, int n) {
    __shared__ int l[1024];
    __shared__ int part[256];
    int b = blockIdx.x, t = threadIdx.x;
    int base = b * 1024;
    #pragma unroll
    for (int i = 0; i < 4; ++i) {
        int idx = base + t + 256 * i;
        l[t + 256 * i] = (idx < n) ? off[idx] : 0;
    }
    __syncthreads();
    int v0 = l[4 * t], v1 = l[4 * t + 1], v2 = l[4 * t + 2], v3 = l[4 * t + 3];
    int p = v0 + v1 + v2 + v3;
    part[t] = p;
    __syncthreads();
    for (int d = 1; d < 256; d <<= 1) {
        int u = (t >= d) ? part[t - d] : 0;
        __syncthreads();
        part[t] += u;
        __syncthreads();
    }
    int ex = bs[b] + ((t == 0) ? 0 : part[t - 1]);
    int e0 = ex, e1 = ex + v0, e2 = e1 + v1, e3 = e2 + v2;
    int idx = base + 4 * t;
    if (idx + 3 < n) {
        ((int4*)(off + idx))[0]    = make_int4(e0, e1, e2, e3);
        ((int4*)(cursor + idx))[0] = make_int4(e0, e1, e2, e3);
    } else {
        if (idx + 0 < n) { off[idx + 0] = e0; cursor[idx + 0] = e0; }
        if (idx + 1 < n) { off[idx + 1] = e1; cursor[idx + 1] = e1; }
        if (idx + 2 < n) { off[idx + 2] = e2; cursor[idx + 2] = e2; }
    }
}

__global__ void scatter_kernel(const int* __restrict__ src, const int* __restrict__ dst,
                               int* __restrict__ cursor, int* __restrict__ srcs, int E) {
    int e = blockIdx.x * blockDim.x + threadIdx.x;
    if (e < E) {
        int d = dst[e];
        int p = atomicAdd(&cursor[d], 1);
        srcs[p] = src[e];
    }
}

// gstart[g] = lower_bound(batch, g) for g in [0, G]
__global__ void gstart_kernel(const int* __restrict__ batch, int* __restrict__ gstart,
                              int n, int g) {
    int i = blockIdx.x * blockDim.x + threadIdx.x;
    if (i > g) return;
    int lo = 0, hi = n;
    while (lo < hi) { int m = (lo + hi) >> 1; if (batch[m] < i) lo = m + 1; else hi = m; }
    gstart[i] = lo;
}

// w_eff[k] = sum_j W2[k][j]*fcw[j]; w_eff[128] = b2.fcw
__global__ void weff_kernel(const float* __restrict__ W2, const float* __restrict__ b2,
                            const float* __restrict__ fcw, float* __restrict__ weff) {
    int tid = threadIdx.x, lane = tid & 63, wave = tid >> 6;
    float2 f2 = ((const float2*)fcw)[lane];
    for (int r = wave; r < 128; r += 4) {
        float2 w = ((const float2*)(W2 + r * FEAT))[lane];
        float d = w.x * f2.x + w.y * f2.y;
        #pragma unroll
        for (int s = 32; s; s >>= 1) d += __shfl_down(d, s, 64);
        if (lane == 0) weff[r] = d;
    }
    if (wave == 0) {
        float2 b = ((const float2*)b2)[lane];
        float d = b.x * f2.x + b.y * f2.y;
        #pragma unroll
        for (int s = 32; s; s >>= 1) d += __shfl_down(d, s, 64);
        if (lane == 0) weff[128] = d;
    }
}

// ---- weight prep: Wswz[mat][c][chunk^(c&7)][j] = bf16(W[8*chunk+j][c]) ----
__global__ void wprep_kernel(const float* __restrict__ W0, const float* __restrict__ W1,
                             const float* __restrict__ W2, const float* __restrict__ W3,
                             const float* __restrict__ W4, unsigned short* __restrict__ Wswz) {
    int gid = blockIdx.x * 256 + threadIdx.x;
    if (gid >= 5 * 2048) return;
    int mat = gid >> 11;
    int task = gid & 2047;
    int c = task >> 4, m = task & 15;
    const float* W = (mat == 0) ? W0 : (mat == 1) ? W1 : (mat == 2) ? W2 : (mat == 3) ? W3 : W4;
    unsigned short* dst = Wswz + mat * 16384 + c * 128 + ((m ^ (c & 7)) << 3);
    #pragma unroll
    for (int j = 0; j < 8; ++j) dst[j] = f2bf(W[(8 * m + j) * FEAT + c]);
}

// ---- cast x (fp32) -> packed bf16 table ----
__global__ void xbf_kernel(const float* __restrict__ x, unsigned int* __restrict__ xbf,
                           long total_pairs) {
    long i = (long)blockIdx.x * blockDim.x + threadIdx.x;
    if (i >= total_pairs) return;
    float2 v = ((const float2*)x)[i];
    xbf[i] = (unsigned int)f2bf(v.x) | ((unsigned int)f2bf(v.y) << 16);
}

// ---------------- aggregation + (1+eps)*h -> bf16 pre ----------------
// one wave per node; lane l reads packed dword = feats [2l,2l+1] of a 256B bf16 row.
__global__ void agg_kernel(const unsigned int* __restrict__ h, const int* __restrict__ off,
                           const int* __restrict__ srcs, const float* __restrict__ eps_p,
                           unsigned int* __restrict__ pre_bf, int n) {
    int wave = (int)((blockIdx.x * (size_t)blockDim.x + threadIdx.x) >> 6);
    int lane = threadIdx.x & 63;
    if (wave >= n) return;
    float eps1 = 1.0f + eps_p[0];
    float2 self = bfpair(h[(size_t)wave * 64 + lane]);
    float2 acc0 = make_float2(self.x * eps1, self.y * eps1);
    float2 acc1 = make_float2(0.f, 0.f);
    float2 acc2 = make_float2(0.f, 0.f);
    float2 acc3 = make_float2(0.f, 0.f);
    int j0 = off[wave], j1 = off[wave + 1];
    int j = j0;
    for (; j + 8 <= j1; j += 8) {
        int s0 = srcs[j + 0], s1 = srcs[j + 1], s2 = srcs[j + 2], s3 = srcs[j + 3];
        int s4 = srcs[j + 4], s5 = srcs[j + 5], s6 = srcs[j + 6], s7 = srcs[j + 7];
        unsigned int u0 = h[(size_t)s0 * 64 + lane];
        unsigned int u1 = h[(size_t)s1 * 64 + lane];
        unsigned int u2 = h[(size_t)s2 * 64 + lane];
        unsigned int u3 = h[(size_t)s3 * 64 + lane];
        unsigned int u4 = h[(size_t)s4 * 64 + lane];
        unsigned int u5 = h[(size_t)s5 * 64 + lane];
        unsigned int u6 = h[(size_t)s6 * 64 + lane];
        unsigned int u7 = h[(size_t)s7 * 64 + lane];
        float2 v0 = bfpair(u0), v1 = bfpair(u1), v2 = bfpair(u2), v3 = bfpair(u3);
        float2 v4 = bfpair(u4), v5 = bfpair(u5), v6 = bfpair(u6), v7 = bfpair(u7);
        acc0.x += v0.x; acc0.y += v0.y;  acc1.x += v1.x; acc1.y += v1.y;
        acc2.x += v2.x; acc2.y += v2.y;  acc3.x += v3.x; acc3.y += v3.y;
        acc0.x += v4.x; acc0.y += v4.y;  acc1.x += v5.x; acc1.y += v5.y;
        acc2.x += v6.x; acc2.y += v6.y;  acc3.x += v7.x; acc3.y += v7.y;
    }
    for (; j < j1; ++j) {
        int s = srcs[j];
        float2 v = bfpair(h[(size_t)s * 64 + lane]);
        acc0.x += v.x; acc0.y += v.y;
    }
    acc0.x += acc1.x + acc2.x + acc3.x;
    acc0.y += acc1.y + acc2.y + acc3.y;
    unsigned int packed = (unsigned int)f2bf(acc0.x) | ((unsigned int)f2bf(acc0.y) << 16);
    pre_bf[(size_t)wave * 64 + lane] = packed;
}

// ---------------- bf16 MFMA GEMM: out[n,128] = A[n,128] @ W[128,128] + b ----
template <int RELU, int OUT_BF16>
__global__ __launch_bounds__(256) void mfma_mlp_kernel(
    const unsigned short* __restrict__ A, const unsigned short* __restrict__ Wswz,
    const float* __restrict__ bias, void* __restrict__ outp, int n) {
    __shared__ int4 Wl4[2048];   // 32KB: swizzled W
    int tid = threadIdx.x;
    const int4* ws4 = (const int4*)Wswz;
    #pragma unroll
    for (int i = 0; i < 8; ++i) Wl4[i * 256 + tid] = ws4[i * 256 + tid];
    __syncthreads();
    const unsigned short* Wl = (const unsigned short*)Wl4;

    int lane = tid & 63, wave = tid >> 6;
    int q = lane >> 4, c15 = lane & 15;
    int r0 = blockIdx.x * 64 + wave * 16;
    int arow = r0 + c15;
    bool rv = arow < n;
    const bf16x8* ap = (const bf16x8*)(A + (size_t)arow * FEAT + q * 8);

    f32x4 zf = {0.f, 0.f, 0.f, 0.f};
    f32x4 acc[8];
    #pragma unroll
    for (int i = 0; i < 8; ++i) acc[i] = zf;
    bf16x8 zero8 = {0, 0, 0, 0, 0, 0, 0, 0};

    #pragma unroll
    for (int k0 = 0; k0 < 4; ++k0) {            // k base = 32*k0
        bf16x8 a = rv ? ap[k0 * 4] : zero8;     // A[arow][32k0 + 8q .. +7]
        int m = k0 * 4 + q;                     // chunk index
        #pragma unroll
        for (int nt = 0; nt < 8; ++nt) {
            int col = nt * 16 + c15;
            bf16x8 b = *(const bf16x8*)&Wl[col * 128 + ((m ^ (col & 7)) << 3)];
            acc[nt] = __builtin_amdgcn_mfma_f32_16x16x32_bf16(a, b, acc[nt], 0, 0, 0);
        }
    }

    int orow0 = r0 + q * 4;
    #pragma unroll
    for (int nt = 0; nt < 8; ++nt) {
        int col = nt * 16 + c15;
        float bv = bias[col];
        #pragma unroll
        for (int r = 0; r < 4; ++r) {
            int ro = orow0 + r;
            if (ro < n) {
                float v = acc[nt][r] + bv;
                if (RELU) v = fmaxf(v, 0.f);
                if (OUT_BF16) ((unsigned short*)outp)[(size_t)ro * FEAT + col] = f2bf(v);
                else          ((float*)outp)[(size_t)ro * FEAT + col] = v;
            }
        }
    }
}

// ---------------- pooling: one block per graph, segmented dot t . w_eff --------
__global__ __launch_bounds__(256) void pool_kernel(const float* __restrict__ t,
    const int* __restrict__ gstart, const float* __restrict__ weff,
    const float* __restrict__ fcb, float* __restrict__ out, int G) {
    int g = blockIdx.x;
    int tid = threadIdx.x, lane = tid & 63, wave = tid >> 6;
    int s0 = gstart[g], s1 = gstart[g + 1];
    int cnt = s1 - s0;
    float2 w2 = ((const float2*)weff)[lane];
    float acc = 0.f;
    for (int nidx = s0 + wave; nidx < s1; nidx += 4) {
        float2 v = ((const float2*)t)[(size_t)nidx * 64 + lane];
        acc += v.x * w2.x + v.y * w2.y;
    }
    #pragma unroll
    for (int d = 32; d; d >>= 1) acc += __shfl_down(acc, d, 64);
    __shared__ float ws[4];
    if (lane == 0) ws[wave] = acc;
    __syncthreads();
    if (tid == 0) {
        float total = ws[0] + ws[1] + ws[2] + ws[3];
        out[g] = (cnt > 0) ? total / (float)cnt + weff[128] + fcb[0] : fcb[0];
    }
}

static inline size_t align256(size_t x) { return (x + 255) & ~(size_t)255; }

extern "C" void kernel_launch(void* const* d_in, const int* in_sizes, int n_in,
                              void* d_out, int out_size, void* d_ws, size_t ws_size,
                              hipStream_t stream) {
    const float* x      = (const float*)d_in[0];
    const int*   ei     = (const int*)d_in[1];
    const int*   batch  = (const int*)d_in[2];
    const float* W1[3]  = {(const float*)d_in[3],  (const float*)d_in[8],  (const float*)d_in[13]};
    const float* b1[3]  = {(const float*)d_in[4],  (const float*)d_in[9],  (const float*)d_in[14]};
    const float* W2[3]  = {(const float*)d_in[5],  (const float*)d_in[10], (const float*)d_in[15]};
    const float* b2[3]  = {(const float*)d_in[6],  (const float*)d_in[11], (const float*)d_in[16]};
    const float* eps[3] = {(const float*)d_in[7],  (const float*)d_in[12], (const float*)d_in[17]};
    const float* fcw    = (const float*)d_in[18];
    const float* fcb    = (const float*)d_in[19];
    float* out = (float*)d_out;

    const int N = in_sizes[0] / FEAT;
    const int E = in_sizes[1] / 2;
    const int G = out_size;

    // workspace layout
    char* p = (char*)d_ws;
    int* off    = (int*)p;  p += align256((size_t)(N + 1) * 4);
    int* cursor = (int*)p;  p += align256((size_t)N * 4);
    int* srcs   = (int*)p;  p += align256((size_t)E * 4);
    int* bsums  = (int*)p;  p += align256((size_t)1024 * 4);
    int* gstart = (int*)p;  p += align256((size_t)(G + 1) * 4);
    float* weff = (float*)p; p += align256((size_t)256 * 4);
    unsigned short* Wswz = (unsigned short*)p; p += align256((size_t)5 * 16384 * 2);
    unsigned int* x_bf   = (unsigned int*)p;   p += align256((size_t)N * 64 * 4);  // bf16 [N][128]
    unsigned int* pre_bf = (unsigned int*)p;   p += align256((size_t)N * 64 * 4);
    unsigned int* t_bf   = (unsigned int*)p;   p += align256((size_t)N * 64 * 4);
    unsigned int* h_bf   = (unsigned int*)p;   p += align256((size_t)N * 64 * 4);
    float* buf1 = (float*)p; p += align256((size_t)N * FEAT * 4);  // fp32 t (layer 2)
    (void)ws_size; (void)n_in;

    const int* src = ei;        // edge_index[0]
    const int* dst = ei + E;    // edge_index[1]

    hipMemsetAsync(off, 0, (size_t)(N + 1) * 4, stream);

    // CSR build (reused for all 3 layers) + weight prep + x cast
    const int nb = (N + 1023) / 1024;
    hist_kernel<<<(E + 255) / 256, 256, 0, stream>>>(dst, off, E);
    block_sum_kernel<<<nb, 256, 0, stream>>>(off, bsums, N);
    scan_blocksums_kernel<<<1, 1024, 0, stream>>>(bsums, nb, off, N);
    block_scan_kernel<<<nb, 256, 0, stream>>>(off, cursor, bsums, N);
    scatter_kernel<<<(E + 255) / 256, 256, 0, stream>>>(src, dst, cursor, srcs, E);
    gstart_kernel<<<(G + 256) / 256, 256, 0, stream>>>(batch, gstart, N, G);
    weff_kernel<<<1, 256, 0, stream>>>(W2[2], b2[2], fcw, weff);
    wprep_kernel<<<40, 256, 0, stream>>>(W1[0], W2[0], W1[1], W2[1], W1[2], Wswz);
    long pairs = (long)N * 64;
    xbf_kernel<<<(int)((pairs + 255) / 256), 256, 0, stream>>>(x, x_bf, pairs);

    const int aggBlocks  = (N + 3) / 4;
    const int gemmBlocks = (N + 63) / 64;
    const unsigned short* Wz[5] = {Wswz, Wswz + 16384, Wswz + 2 * 16384,
                                   Wswz + 3 * 16384, Wswz + 4 * 16384};

    // layers 0,1: agg(bf16 table) -> gemm1(bf16 out) -> gemm2(bf16 h out, relu)
    const unsigned int* h = x_bf;
    for (int i = 0; i < 2; ++i) {
        agg_kernel<<<aggBlocks, 256, 0, stream>>>(h, off, srcs, eps[i], pre_bf, N);
        mfma_mlp_kernel<1, 1><<<gemmBlocks, 256, 0, stream>>>(
            (const unsigned short*)pre_bf, Wz[2 * i], b1[i], (void*)t_bf, N);
        mfma_mlp_kernel<1, 1><<<gemmBlocks, 256, 0, stream>>>(
            (const unsigned short*)t_bf, Wz[2 * i + 1], b2[i], (void*)h_bf, N);
        h = h_bf;
    }
    // layer 2: agg -> gemm1 (fp32 t out); W2_2+fc folded into pool via weff
    agg_kernel<<<aggBlocks, 256, 0, stream>>>(h, off, srcs, eps[2], pre_bf, N);
    mfma_mlp_kernel<1, 0><<<gemmBlocks, 256, 0, stream>>>(
        (const unsigned short*)pre_bf, Wz[4], b1[2], (void*)buf1, N);

    pool_kernel<<<G, 256, 0, stream>>>(buf1, gstart, weff, fcb, out, G);
}

// Round 7
// 350.366 us; speedup vs baseline: 2.4442x; 1.1679x over previous
//
#include <hip/hip_runtime.h>

// GIN regressor: 3x [segment-sum aggregation -> (1+eps)*x+agg -> Linear/ReLU/Linear]
// -> global mean pool -> fc.
// CSR built once per call via coarse-bucket counting sort (clustered writes: the
// round-6 flat scatter showed 52MB HBM write for a 3.2MB payload). Aggregation is
// gather-only over bf16 tables. GEMMs = bf16 MFMA (fp32 accum, pre-swizzled W).
// Layer-2: second GEMM folded into pool (weff = W2@fcw); layer-2 first GEMM's
// epilogue computes the pooled per-graph sums directly (no per-node output).

#define FEAT 128
#define BCAP 2048          // coarse-bucket capacity (mean load ~1024, 5-sigma ~1190)

typedef short  bf16x8 __attribute__((ext_vector_type(8)));
typedef float  f32x4  __attribute__((ext_vector_type(4)));

__device__ inline unsigned short f2bf(float f) {  // round-to-nearest-even fp32->bf16
    unsigned int u = __float_as_uint(f);
    u = (u + 0x7FFFu + ((u >> 16) & 1u)) >> 16;
    return (unsigned short)u;
}
__device__ inline float2 bfpair(unsigned int u) { // packed 2x bf16 -> 2x fp32
    float2 r;
    r.x = __uint_as_float(u << 16);
    r.y = __uint_as_float(u & 0xffff0000u);
    return r;
}

// ---------------- CSR build: coarse-bucket counting sort ----------------
// Phase 1: bin edges by dst>>6. Pair packs src (<2^26) and dst&63.
__global__ void bucket_kernel(const int* __restrict__ src, const int* __restrict__ dst,
                              int* __restrict__ bcnt, unsigned int* __restrict__ bpairs,
                              int E) {
    int e = blockIdx.x * blockDim.x + threadIdx.x;
    if (e >= E) return;
    int d = dst[e], s = src[e];
    int cb = d >> 6;
    int p = atomicAdd(&bcnt[cb * 16], 1);       // 64B-padded counters
    if (p < BCAP) bpairs[(size_t)cb * BCAP + p] = ((unsigned int)s << 6) | (unsigned int)(d & 63);
}

// Phase 2: per-bucket LDS histogram -> node degrees (replaces global-atomic hist).
__global__ __launch_bounds__(256) void deg_kernel(const int* __restrict__ bcnt,
                                                  const unsigned int* __restrict__ bpairs,
                                                  int* __restrict__ off, int n) {
    __shared__ int lh[64];
    int b = blockIdx.x, tid = threadIdx.x;
    if (tid < 64) lh[tid] = 0;
    __syncthreads();
    int cnt = bcnt[b * 16]; if (cnt > BCAP) cnt = BCAP;
    const unsigned int* bp = bpairs + (size_t)b * BCAP;
    for (int i = tid; i < cnt; i += 256) atomicAdd(&lh[bp[i] & 63u], 1);
    __syncthreads();
    if (tid < 64) {
        int node = b * 64 + tid;
        if (node < n) off[node] = lh[tid];
    }
}

// Phase A: blocksums[b] = sum(off[b*1024 .. +1023])
__global__ void block_sum_kernel(const int* __restrict__ off, int* __restrict__ bs, int n) {
    int b = blockIdx.x, t = threadIdx.x;   // 256 threads
    int base = b * 1024;
    int s = 0;
    #pragma unroll
    for (int i = 0; i < 4; ++i) {
        int idx = base + t + 256 * i;
        if (idx < n) s += off[idx];
    }
    #pragma unroll
    for (int d = 32; d; d >>= 1) s += __shfl_down(s, d, 64);
    __shared__ int ws[4];
    if ((t & 63) == 0) ws[t >> 6] = s;
    __syncthreads();
    if (t == 0) bs[b] = ws[0] + ws[1] + ws[2] + ws[3];
}

__global__ void scan_blocksums_kernel(int* __restrict__ bs, int nb,
                                      int* __restrict__ off, int n) {
    __shared__ int l[1024];
    int t = threadIdx.x;
    int v = (t < nb) ? bs[t] : 0;
    l[t] = v;
    __syncthreads();
    for (int d = 1; d < 1024; d <<= 1) {
        int u = (t >= d) ? l[t - d] : 0;
        __syncthreads();
        l[t] += u;
        __syncthreads();
    }
    if (t < nb) bs[t] = (t == 0) ? 0 : l[t - 1];
    if (t == 1023) off[n] = l[1023];
}

__global__ __launch_bounds__(256) void block_scan_kernel(
    int* __restrict__ off, const int* __restrict__ bs, int n) {
    __shared__ int l[1024];
    __shared__ int part[256];
    int b = blockIdx.x, t = threadIdx.x;
    int base = b * 1024;
    #pragma unroll
    for (int i = 0; i < 4; ++i) {
        int idx = base + t + 256 * i;
        l[t + 256 * i] = (idx < n) ? off[idx] : 0;
    }
    __syncthreads();
    int v0 = l[4 * t], v1 = l[4 * t + 1], v2 = l[4 * t + 2], v3 = l[4 * t + 3];
    int p = v0 + v1 + v2 + v3;
    part[t] = p;
    __syncthreads();
    for (int d = 1; d < 256; d <<= 1) {
        int u = (t >= d) ? part[t - d] : 0;
        __syncthreads();
        part[t] += u;
        __syncthreads();
    }
    int ex = bs[b] + ((t == 0) ? 0 : part[t - 1]);
    int e0 = ex, e1 = ex + v0, e2 = e1 + v1, e3 = e2 + v2;
    int idx = base + 4 * t;
    if (idx + 3 < n) {
        ((int4*)(off + idx))[0] = make_int4(e0, e1, e2, e3);
    } else {
        if (idx + 0 < n) off[idx + 0] = e0;
        if (idx + 1 < n) off[idx + 1] = e1;
        if (idx + 2 < n) off[idx + 2] = e2;
    }
}

// Phase 3: per-bucket scatter with LDS cursors; writes confined to a ~4KB region.
__global__ __launch_bounds__(256) void bucket_scatter_kernel(
    const int* __restrict__ bcnt, const unsigned int* __restrict__ bpairs,
    const int* __restrict__ off, int* __restrict__ srcs, int n) {
    __shared__ int lcur[64];
    int b = blockIdx.x, tid = threadIdx.x;
    if (tid < 64) {
        int node = b * 64 + tid;
        lcur[tid] = (node < n) ? off[node] : 0;
    }
    __syncthreads();
    int cnt = bcnt[b * 16]; if (cnt > BCAP) cnt = BCAP;
    const unsigned int* bp = bpairs + (size_t)b * BCAP;
    for (int i = tid; i < cnt; i += 256) {
        unsigned int pr = bp[i];
        int pos = atomicAdd(&lcur[pr & 63u], 1);
        srcs[pos] = (int)(pr >> 6);
    }
}

// ---------------- fused setup: xbf | gstart | weff | wprep ----------------
__global__ __launch_bounds__(256) void setup_kernel(
    const float* __restrict__ x, unsigned int* __restrict__ xbf, long pairs, int nxb,
    const int* __restrict__ batch, int* __restrict__ gstart, int n, int G,
    const float* __restrict__ W2f, const float* __restrict__ b2f,
    const float* __restrict__ fcw, float* __restrict__ weff,
    const float* __restrict__ W0, const float* __restrict__ W1,
    const float* __restrict__ W2, const float* __restrict__ W3,
    const float* __restrict__ W4, unsigned short* __restrict__ Wswz) {
    int b = blockIdx.x, tid = threadIdx.x;
    if (b < nxb) {                       // cast x -> packed bf16
        long i = (long)b * 256 + tid;
        if (i < pairs) {
            float2 v = ((const float2*)x)[i];
            xbf[i] = (unsigned int)f2bf(v.x) | ((unsigned int)f2bf(v.y) << 16);
        }
    } else if (b < nxb + 2) {            // gstart[g] = lower_bound(batch, g)
        int i = (b - nxb) * 256 + tid;
        if (i <= G) {
            int lo = 0, hi = n;
            while (lo < hi) { int m = (lo + hi) >> 1; if (batch[m] < i) lo = m + 1; else hi = m; }
            gstart[i] = lo;
        }
    } else if (b == nxb + 2) {           // weff = W2@fcw ; weff[128] = b2.fcw
        int lane = tid & 63, wave = tid >> 6;
        float2 f2 = ((const float2*)fcw)[lane];
        for (int r = wave; r < 128; r += 4) {
            float2 w = ((const float2*)(W2f + r * FEAT))[lane];
            float d = w.x * f2.x + w.y * f2.y;
            #pragma unroll
            for (int s = 32; s; s >>= 1) d += __shfl_down(d, s, 64);
            if (lane == 0) weff[r] = d;
        }
        if (wave == 0) {
            float2 bb = ((const float2*)b2f)[lane];
            float d = bb.x * f2.x + bb.y * f2.y;
            #pragma unroll
            for (int s = 32; s; s >>= 1) d += __shfl_down(d, s, 64);
            if (lane == 0) weff[128] = d;
        }
    } else {                             // wprep: swizzled bf16 weights
        int gid = (b - nxb - 3) * 256 + tid;
        if (gid < 5 * 2048) {
            int mat = gid >> 11;
            int task = gid & 2047;
            int c = task >> 4, m = task & 15;
            const float* W = (mat == 0) ? W0 : (mat == 1) ? W1 : (mat == 2) ? W2 :
                             (mat == 3) ? W3 : W4;
            unsigned short* dp = Wswz + mat * 16384 + c * 128 + ((m ^ (c & 7)) << 3);
            #pragma unroll
            for (int j = 0; j < 8; ++j) dp[j] = f2bf(W[(8 * m + j) * FEAT + c]);
        }
    }
}

// ---------------- aggregation + (1+eps)*h -> bf16 pre ----------------
__global__ void agg_kernel(const unsigned int* __restrict__ h, const int* __restrict__ off,
                           const int* __restrict__ srcs, const float* __restrict__ eps_p,
                           unsigned int* __restrict__ pre_bf, int n) {
    int wave = (int)((blockIdx.x * (size_t)blockDim.x + threadIdx.x) >> 6);
    int lane = threadIdx.x & 63;
    if (wave >= n) return;
    float eps1 = 1.0f + eps_p[0];
    float2 self = bfpair(h[(size_t)wave * 64 + lane]);
    float2 acc0 = make_float2(self.x * eps1, self.y * eps1);
    float2 acc1 = make_float2(0.f, 0.f);
    float2 acc2 = make_float2(0.f, 0.f);
    float2 acc3 = make_float2(0.f, 0.f);
    int j0 = off[wave], j1 = off[wave + 1];
    int j = j0;
    for (; j + 8 <= j1; j += 8) {
        int s0 = srcs[j + 0], s1 = srcs[j + 1], s2 = srcs[j + 2], s3 = srcs[j + 3];
        int s4 = srcs[j + 4], s5 = srcs[j + 5], s6 = srcs[j + 6], s7 = srcs[j + 7];
        unsigned int u0 = h[(size_t)s0 * 64 + lane];
        unsigned int u1 = h[(size_t)s1 * 64 + lane];
        unsigned int u2 = h[(size_t)s2 * 64 + lane];
        unsigned int u3 = h[(size_t)s3 * 64 + lane];
        unsigned int u4 = h[(size_t)s4 * 64 + lane];
        unsigned int u5 = h[(size_t)s5 * 64 + lane];
        unsigned int u6 = h[(size_t)s6 * 64 + lane];
        unsigned int u7 = h[(size_t)s7 * 64 + lane];
        float2 v0 = bfpair(u0), v1 = bfpair(u1), v2 = bfpair(u2), v3 = bfpair(u3);
        float2 v4 = bfpair(u4), v5 = bfpair(u5), v6 = bfpair(u6), v7 = bfpair(u7);
        acc0.x += v0.x; acc0.y += v0.y;  acc1.x += v1.x; acc1.y += v1.y;
        acc2.x += v2.x; acc2.y += v2.y;  acc3.x += v3.x; acc3.y += v3.y;
        acc0.x += v4.x; acc0.y += v4.y;  acc1.x += v5.x; acc1.y += v5.y;
        acc2.x += v6.x; acc2.y += v6.y;  acc3.x += v7.x; acc3.y += v7.y;
    }
    for (; j < j1; ++j) {
        int s = srcs[j];
        float2 v = bfpair(h[(size_t)s * 64 + lane]);
        acc0.x += v.x; acc0.y += v.y;
    }
    acc0.x += acc1.x + acc2.x + acc3.x;
    acc0.y += acc1.y + acc2.y + acc3.y;
    pre_bf[(size_t)wave * 64 + lane] =
        (unsigned int)f2bf(acc0.x) | ((unsigned int)f2bf(acc0.y) << 16);
}

// ---------------- bf16 MFMA GEMM (+ReLU). MODE 1: bf16 store. MODE 2: fused pool ----
template <int MODE>
__global__ __launch_bounds__(256) void mfma_mlp_kernel(
    const unsigned short* __restrict__ A, const unsigned short* __restrict__ Wswz,
    const float* __restrict__ bias, unsigned short* __restrict__ outbf,
    const int* __restrict__ batch, const float* __restrict__ weff,
    float* __restrict__ sums, int n) {
    __shared__ int4 Wl4[2048];   // 32KB swizzled W
    int tid = threadIdx.x;
    const int4* ws4 = (const int4*)Wswz;
    #pragma unroll
    for (int i = 0; i < 8; ++i) Wl4[i * 256 + tid] = ws4[i * 256 + tid];
    __syncthreads();
    const unsigned short* Wl = (const unsigned short*)Wl4;

    int lane = tid & 63, wave = tid >> 6;
    int q = lane >> 4, c15 = lane & 15;
    int r0 = blockIdx.x * 64 + wave * 16;
    int arow = r0 + c15;
    bool rv = arow < n;
    const bf16x8* ap = (const bf16x8*)(A + (size_t)arow * FEAT + q * 8);

    f32x4 zf = {0.f, 0.f, 0.f, 0.f};
    f32x4 acc[8];
    #pragma unroll
    for (int i = 0; i < 8; ++i) acc[i] = zf;
    bf16x8 zero8 = {0, 0, 0, 0, 0, 0, 0, 0};

    #pragma unroll
    for (int k0 = 0; k0 < 4; ++k0) {
        bf16x8 a = rv ? ap[k0 * 4] : zero8;
        int m = k0 * 4 + q;
        #pragma unroll
        for (int nt = 0; nt < 8; ++nt) {
            int col = nt * 16 + c15;
            bf16x8 b = *(const bf16x8*)&Wl[col * 128 + ((m ^ (col & 7)) << 3)];
            acc[nt] = __builtin_amdgcn_mfma_f32_16x16x32_bf16(a, b, acc[nt], 0, 0, 0);
        }
    }

    int orow0 = r0 + q * 4;
    if (MODE == 1) {
        #pragma unroll
        for (int nt = 0; nt < 8; ++nt) {
            int col = nt * 16 + c15;
            float bv = bias[col];
            #pragma unroll
            for (int r = 0; r < 4; ++r) {
                int ro = orow0 + r;
                if (ro < n) {
                    float v = fmaxf(acc[nt][r] + bv, 0.f);
                    outbf[(size_t)ro * FEAT + col] = f2bf(v);
                }
            }
        }
    } else {
        // fused pool: rowdot = relu(row)·weff ; per-graph LDS accumulation.
        __shared__ float gsum[64];
        int r0b = blockIdx.x * 64;
        int lastn = r0b + 63 < n - 1 ? r0b + 63 : n - 1;
        int gmin = batch[r0b];
        int gmax = batch[lastn];
        int span = gmax - gmin + 1;
        bool lds_ok = (span <= 64);
        if (lds_ok) for (int i = tid; i < span; i += 256) gsum[i] = 0.f;
        __syncthreads();
        float rowdot[4] = {0.f, 0.f, 0.f, 0.f};
        #pragma unroll
        for (int nt = 0; nt < 8; ++nt) {
            int col = nt * 16 + c15;
            float bv = bias[col];
            float wv = weff[col];
            #pragma unroll
            for (int r = 0; r < 4; ++r)
                rowdot[r] += fmaxf(acc[nt][r] + bv, 0.f) * wv;
        }
        #pragma unroll
        for (int r = 0; r < 4; ++r) {
            float v = rowdot[r];
            v += __shfl_xor(v, 1, 64);
            v += __shfl_xor(v, 2, 64);
            v += __shfl_xor(v, 4, 64);
            v += __shfl_xor(v, 8, 64);
            if (c15 == 0) {
                int node = orow0 + r;
                if (node < n) {
                    int g = batch[node];
                    if (lds_ok) atomicAdd(&gsum[g - gmin], v);
                    else        atomicAdd(&sums[g], v);
                }
            }
        }
        __syncthreads();
        if (lds_ok)
            for (int i = tid; i < span; i += 256) atomicAdd(&sums[gmin + i], gsum[i]);
    }
}

// ---------------- finalize: out[g] = sums/cnt + b2.fcw + fcb ----------------
__global__ void finalize_kernel(const float* __restrict__ sums, const int* __restrict__ gstart,
                                const float* __restrict__ weff, const float* __restrict__ fcb,
                                float* __restrict__ out, int G) {
    int g = blockIdx.x * blockDim.x + threadIdx.x;
    if (g >= G) return;
    int cnt = gstart[g + 1] - gstart[g];
    out[g] = (cnt > 0) ? sums[g] / (float)cnt + weff[128] + fcb[0] : fcb[0];
}

static inline size_t align256(size_t x) { return (x + 255) & ~(size_t)255; }

extern "C" void kernel_launch(void* const* d_in, const int* in_sizes, int n_in,
                              void* d_out, int out_size, void* d_ws, size_t ws_size,
                              hipStream_t stream) {
    const float* x      = (const float*)d_in[0];
    const int*   ei     = (const int*)d_in[1];
    const int*   batch  = (const int*)d_in[2];
    const float* W1[3]  = {(const float*)d_in[3],  (const float*)d_in[8],  (const float*)d_in[13]};
    const float* b1[3]  = {(const float*)d_in[4],  (const float*)d_in[9],  (const float*)d_in[14]};
    const float* W2[3]  = {(const float*)d_in[5],  (const float*)d_in[10], (const float*)d_in[15]};
    const float* b2[3]  = {(const float*)d_in[6],  (const float*)d_in[11], (const float*)d_in[16]};
    const float* eps[3] = {(const float*)d_in[7],  (const float*)d_in[12], (const float*)d_in[17]};
    const float* fcw    = (const float*)d_in[18];
    const float* fcb    = (const float*)d_in[19];
    float* out = (float*)d_out;

    const int N = in_sizes[0] / FEAT;
    const int E = in_sizes[1] / 2;
    const int G = out_size;
    const int nbuckets = (N + 63) >> 6;

    // workspace layout
    char* p = (char*)d_ws;
    int* off    = (int*)p;  p += align256((size_t)(N + 1) * 4);
    int* srcs   = (int*)p;  p += align256((size_t)E * 4);
    int* bsums  = (int*)p;  p += align256((size_t)1024 * 4);
    int* gstart = (int*)p;  p += align256((size_t)(G + 1) * 4);
    float* weff = (float*)p; p += align256((size_t)256 * 4);
    unsigned short* Wswz = (unsigned short*)p; p += align256((size_t)5 * 16384 * 2);
    float* sums = (float*)p;                     // zero-init region start
    char* z0 = (char*)sums;
    p += align256((size_t)G * 4);
    int* bcnt = (int*)p; p += align256((size_t)nbuckets * 16 * 4);
    size_t zbytes = (size_t)(p - z0);            // sums + bcnt in one memset
    unsigned int* bpairs = (unsigned int*)p;     p += align256((size_t)nbuckets * BCAP * 4);
    unsigned int* x_bf   = (unsigned int*)p;     p += align256((size_t)N * 64 * 4);
    unsigned int* pre_bf = (unsigned int*)p;     p += align256((size_t)N * 64 * 4);
    unsigned int* t_bf   = (unsigned int*)p;     p += align256((size_t)N * 64 * 4);
    unsigned int* h_bf   = (unsigned int*)p;     p += align256((size_t)N * 64 * 4);
    (void)ws_size; (void)n_in;

    const int* src = ei;        // edge_index[0]
    const int* dst = ei + E;    // edge_index[1]

    hipMemsetAsync(z0, 0, zbytes, stream);

    // CSR build: bucket -> deg -> scan -> bucket_scatter
    const int nb = (N + 1023) / 1024;
    bucket_kernel<<<(E + 255) / 256, 256, 0, stream>>>(src, dst, bcnt, bpairs, E);
    deg_kernel<<<nbuckets, 256, 0, stream>>>(bcnt, bpairs, off, N);
    block_sum_kernel<<<nb, 256, 0, stream>>>(off, bsums, N);
    scan_blocksums_kernel<<<1, 1024, 0, stream>>>(bsums, nb, off, N);
    block_scan_kernel<<<nb, 256, 0, stream>>>(off, bsums, N);
    bucket_scatter_kernel<<<nbuckets, 256, 0, stream>>>(bcnt, bpairs, off, srcs, N);

    // fused setup (independent of CSR): xbf | gstart | weff | wprep
    long pairs = (long)N * 64;
    int nxb = (int)((pairs + 255) / 256);
    setup_kernel<<<nxb + 43, 256, 0, stream>>>(
        x, x_bf, pairs, nxb, batch, gstart, N, G,
        W2[2], b2[2], fcw, weff,
        W1[0], W2[0], W1[1], W2[1], W1[2], Wswz);

    const int aggBlocks  = (N + 3) / 4;
    const int gemmBlocks = (N + 63) / 64;
    const unsigned short* Wz[5] = {Wswz, Wswz + 16384, Wswz + 2 * 16384,
                                   Wswz + 3 * 16384, Wswz + 4 * 16384};

    // layers 0,1: agg -> gemm1(bf16) -> gemm2(bf16)
    const unsigned int* h = x_bf;
    for (int i = 0; i < 2; ++i) {
        agg_kernel<<<aggBlocks, 256, 0, stream>>>(h, off, srcs, eps[i], pre_bf, N);
        mfma_mlp_kernel<1><<<gemmBlocks, 256, 0, stream>>>(
            (const unsigned short*)pre_bf, Wz[2 * i], b1[i], (unsigned short*)t_bf,
            nullptr, nullptr, nullptr, N);
        mfma_mlp_kernel<1><<<gemmBlocks, 256, 0, stream>>>(
            (const unsigned short*)t_bf, Wz[2 * i + 1], b2[i], (unsigned short*)h_bf,
            nullptr, nullptr, nullptr, N);
        h = h_bf;
    }
    // layer 2: agg -> gemm1 with fused pooled-dot epilogue (W2_2+fc folded via weff)
    agg_kernel<<<aggBlocks, 256, 0, stream>>>(h, off, srcs, eps[2], pre_bf, N);
    mfma_mlp_kernel<2><<<gemmBlocks, 256, 0, stream>>>(
        (const unsigned short*)pre_bf, Wz[4], b1[2], nullptr,
        batch, weff, sums, N);

    finalize_kernel<<<(G + 255) / 256, 256, 0, stream>>>(sums, gstart, weff, fcb, out, G);
}